// Round 5
// baseline (1730.865 us; speedup 1.0000x reference)
//
#include <hip/hip_runtime.h>
#include <cstdint>
#include <cstddef>

typedef _Float16 f16;
typedef __attribute__((ext_vector_type(4))) _Float16 f16x4;
typedef __attribute__((ext_vector_type(8))) _Float16 f16x8;
typedef __attribute__((ext_vector_type(4))) float f32x4;
typedef uint32_t u32;
typedef uint16_t u16;
typedef unsigned long long u64;

#define N_NODES 8192
#define T_STEPS 32
#define H_DIM   256
#define N_EDGES 1024
#define NNZ_    65536

// LDS row stride: 36 f16 = 18 words; mr*18 mod 32 has 16 distinct residues
// -> conflict-free fragment reads (vs 40 f16 = 20 words, period 8, 2-4x conflicts).
#define LSTR 36

__device__ __forceinline__ f16x8 ld8lds(const f16* p) {
  union { f16x8 v8; f16x4 v4[2]; } u;
  u.v4[0] = *reinterpret_cast<const f16x4*>(p);
  u.v4[1] = *reinterpret_cast<const f16x4*>(p + 4);
  return u.v8;
}
__device__ __forceinline__ void st8lds(f16* p, f16x8 v) {
  union { f16x8 v8; f16x4 v4[2]; } u; u.v8 = v;
  *reinterpret_cast<f16x4*>(p) = u.v4[0];
  *reinterpret_cast<f16x4*>(p + 4) = u.v4[1];
}

// ------------------------------------------------------------------
// counting sort of nodes by length, descending. Also emits M_t = #{len>t}.
__global__ void k_sort(const int* __restrict__ len, int* __restrict__ order,
                       int* __restrict__ len_s, int* __restrict__ Mts) {
  __shared__ int hist[33];
  __shared__ int cur[33];
  int tid = threadIdx.x;
  if (tid < 33) hist[tid] = 0;
  __syncthreads();
  for (int i = tid; i < N_NODES; i += 256) {
    int l = len[i]; l = l < 0 ? 0 : (l > 32 ? 32 : l);
    atomicAdd(&hist[l], 1);
  }
  __syncthreads();
  if (tid == 0) {
    int acc = 0;
    for (int l = 32; l >= 0; --l) { cur[l] = acc; acc += hist[l]; }
    for (int t = 0; t < 32; ++t) Mts[t] = cur[t];  // cur[t] = #{len > t}
  }
  __syncthreads();
  for (int i = tid; i < N_NODES; i += 256) {
    int l = len[i]; l = l < 0 ? 0 : (l > 32 ? 32 : l);
    int pos = atomicAdd(&cur[l], 1);
    order[pos] = i; len_s[pos] = l;
  }
}

// Pack GRU weights into MFMA-fragment order so fragment loads are fully
// coalesced (lane-contiguous). Packed layout, per matrix (wih / whh):
//   tile = (kt*16 + jt)*3 + g          (384 tiles of 512 f16 = 1 KB)
//   within-tile offset = (quad*16 + mr)*8 + e  = lane*8 + e
//   source element = W[g*256 + jt*16 + mr][kt*32 + quad*8 + e]
// A wave's fragment load (fixed kt, jt, g) is then base + lane*16B ->
// one contiguous 1 KB read (8 fully-used 128B lines) instead of 64
// partially-used lines (the round-4 L2-amplification bottleneck).
__global__ void k_wpack(const float* __restrict__ wih, const float* __restrict__ whh,
                        f16* __restrict__ wihp, f16* __restrict__ whhp) {
  int i = blockIdx.x * 256 + threadIdx.x;        // 768*256 = 196608 elems
  int tile = i >> 9, within = i & 511;
  int quad = within >> 7, mr = (within >> 3) & 15, e = within & 7;
  int g = tile % 3, t3 = tile / 3;
  int jt = t3 & 15, kt = t3 >> 4;
  int row = g * 256 + jt * 16 + mr;
  int col = kt * 32 + quad * 8 + e;
  wihp[i] = (f16)wih[row * 256 + col];
  whhp[i] = (f16)whh[row * 256 + col];
}

__global__ void k_hist(const int* __restrict__ he, u32* __restrict__ hd, u32* __restrict__ hb) {
  int i = blockIdx.x * 256 + threadIdx.x;
  if (i < NNZ_) {
    atomicAdd(&hd[he[i]], 1u);
    atomicAdd(&hb[he[NNZ_ + i]], 1u);
  }
}

__global__ void k_inv(const u32* __restrict__ hd, const u32* __restrict__ hb,
                      float* __restrict__ dinv, float* __restrict__ binv) {
  int i = blockIdx.x * 256 + threadIdx.x;
  if (i < N_NODES) dinv[i] = hd[i] ? 1.0f / (float)hd[i] : 0.0f;
  if (i < N_EDGES) binv[i] = hb[i] ? 1.0f / (float)hb[i] : 0.0f;
}

// ------------------------------------------------------------------
// Exclusive prefix scan of node/edge histograms -> CSR offsets + cursors.
__global__ void k_scan(const u32* __restrict__ histD, const u32* __restrict__ histB,
                       int* __restrict__ noff, int* __restrict__ eoff,
                       int* __restrict__ ncur, int* __restrict__ ecur) {
  __shared__ int buf[256];
  __shared__ int base;
  int tid = threadIdx.x;
  if (tid == 0) base = 0;
  __syncthreads();
  for (int ch = 0; ch < N_NODES / 256; ++ch) {
    int i = ch * 256 + tid;
    int v = (int)histD[i];
    buf[tid] = v; __syncthreads();
    for (int off = 1; off < 256; off <<= 1) {
      int t = (tid >= off) ? buf[tid - off] : 0; __syncthreads();
      buf[tid] += t; __syncthreads();
    }
    int excl = base + buf[tid] - v;
    noff[i] = excl; ncur[i] = excl;
    __syncthreads();
    if (tid == 255) { base += buf[255]; if (i == N_NODES - 1) noff[N_NODES] = base; }
    __syncthreads();
  }
  if (tid == 0) base = 0;
  __syncthreads();
  for (int ch = 0; ch < N_EDGES / 256; ++ch) {
    int i = ch * 256 + tid;
    int v = (int)histB[i];
    buf[tid] = v; __syncthreads();
    for (int off = 1; off < 256; off <<= 1) {
      int t = (tid >= off) ? buf[tid - off] : 0; __syncthreads();
      buf[tid] += t; __syncthreads();
    }
    int excl = base + buf[tid] - v;
    eoff[i] = excl; ecur[i] = excl;
    __syncthreads();
    if (tid == 255) { base += buf[255]; if (i == N_EDGES - 1) eoff[N_EDGES] = base; }
    __syncthreads();
  }
}

__global__ void k_fill(const int* __restrict__ he, int* __restrict__ ncur,
                       int* __restrict__ ecur, int* __restrict__ nlist,
                       int* __restrict__ elist) {
  int i = blockIdx.x * 256 + threadIdx.x;
  if (i < NNZ_) {
    int node = he[i], edge = he[NNZ_ + i];
    int p1 = atomicAdd(&ecur[edge], 1); nlist[p1] = node;  // per-edge node list
    int p2 = atomicAdd(&ncur[node], 1); elist[p2] = edge;  // per-node edge list
  }
}

// e[edge][c] = Binv[edge] * sum_{node in edge} xw[node][c]   (gather, no atomics)
__global__ __launch_bounds__(256)
void k_edge_gather(const float* __restrict__ xw, const int* __restrict__ eoff,
                   const int* __restrict__ nlist, const float* __restrict__ binv,
                   float* __restrict__ e) {
  int edge = blockIdx.x, c = threadIdx.x;
  int s = eoff[edge], t = eoff[edge + 1];
  __shared__ int nds[256];
  float sum = 0.0f;
  for (int base = s; base < t; base += 256) {
    int nchunk = t - base; if (nchunk > 256) nchunk = 256;
    if (c < nchunk) nds[c] = nlist[base + c];
    __syncthreads();
    for (int k = 0; k < nchunk; ++k)
      sum += xw[(size_t)nds[k] * H_DIM + c];
    __syncthreads();
  }
  e[(size_t)edge * H_DIM + c] = sum * binv[edge];
}

// out[node][c] = prev[node][c] + bias[c] + Dinv[node] * sum_{edge in node} e[edge][c]
__global__ __launch_bounds__(256)
void k_node_gather(const float* __restrict__ e, const int* __restrict__ noff,
                   const int* __restrict__ elist, const float* __restrict__ dinv,
                   const float* __restrict__ prev, const float* __restrict__ bias,
                   float* __restrict__ outp) {
  int node = blockIdx.x, c = threadIdx.x;
  int s = noff[node], t = noff[node + 1];
  __shared__ int eds[64];
  float sum = 0.0f;
  for (int base = s; base < t; base += 64) {
    int nchunk = t - base; if (nchunk > 64) nchunk = 64;
    if (c < nchunk) eds[c] = elist[base + c];
    __syncthreads();
    for (int k = 0; k < nchunk; ++k)
      sum += e[(size_t)eds[k] * H_DIM + c];
    __syncthreads();
  }
  outp[(size_t)node * H_DIM + c] =
      prev[(size_t)node * H_DIM + c] + bias[c] + dinv[node] * sum;
}

// ------------------------------------------------------------------
// Transpose + f16 hi/lo split: src [Mp][Np] f32 -> hiT/loT [Np][Mp] f16.
__global__ __launch_bounds__(256)
void k_tsplit(const float* __restrict__ src, f16* __restrict__ hiT,
              f16* __restrict__ loT, int Mp, int Np, int withLo) {
  __shared__ float tile[64][65];
  int m0 = blockIdx.x * 64, n0 = blockIdx.y * 64;
  int tid = threadIdx.x;
#pragma unroll
  for (int i = 0; i < 4; ++i) {
    int q = tid + 256 * i;             // 1024 float4 = 64 rows x 64 cols
    int row = q >> 4, c4 = (q & 15) << 2;
    float4 v = *reinterpret_cast<const float4*>(&src[(size_t)(m0 + row) * Np + n0 + c4]);
    tile[row][c4] = v.x; tile[row][c4 + 1] = v.y;
    tile[row][c4 + 2] = v.z; tile[row][c4 + 3] = v.w;
  }
  __syncthreads();
#pragma unroll
  for (int i = 0; i < 4; ++i) {
    int q = tid + 256 * i;
    int nrow = q >> 4, mc = (q & 15) << 2;
    f16x4 h, l;
#pragma unroll
    for (int j = 0; j < 4; ++j) {
      float v = tile[mc + j][nrow];
      h[j] = (f16)v;
      l[j] = (f16)(v - (float)h[j]);
    }
    *reinterpret_cast<f16x4*>(&hiT[(size_t)(n0 + nrow) * Mp + m0 + mc]) = h;
    if (withLo)
      *reinterpret_cast<f16x4*>(&loT[(size_t)(n0 + nrow) * Mp + m0 + mc]) = l;
  }
}

// ------------------------------------------------------------------
// Persistent GRU: ONE launch for all 32 time steps.
// Round-5: coalesced packed weights + 64 rows/block.
//  - Round-4 diagnosis: weight fragment loads strided 512 B per lane ->
//    each wave-load touched 64 distinct cache lines (16 B used per line),
//    no L1 retention (98 KB/wave/step vs 32 KB L1) -> 4-8x L2 traffic
//    amplification, ~28 us/step, 85% stall. Packed layout (k_wpack) makes
//    every fragment load lane-contiguous (1 KB per wave-load, 8 full lines).
//  - 128 blocks x 64 rows halves per-row weight traffic (round-3 geometry;
//    its failure causes - spills + amplification - are both fixed now).
//    LDS 111 KB (3 x f16[8][64*LSTR]), 1 block/CU, 8 waves.
//  - Runtime kt loop (unroll disabled), single-buffered 12-frag weight set:
//    proven spill-free in round 4. acc 128 AGPR + ~110 arch VGPR < 256.
//  - h in LDS as f16 hi/lo (hp = hi+lo, ~1e-7 rel err); x nontemporal,
//    register-prefetched one step ahead; `last` store normal.
__global__ __launch_bounds__(512, 2)
void k_gru_all(const float* __restrict__ x, const float* __restrict__ h0,
               float* __restrict__ last,
               const f16* __restrict__ wihp, const f16* __restrict__ whhp,
               const float* __restrict__ bih, const float* __restrict__ bhh,
               const int* __restrict__ order, const int* __restrict__ len_s) {
  __shared__ f16 Xs[8][64 * LSTR];     // x(t) tile, f16, per-32k-chunk layout
  __shared__ f16 Hh[8][64 * LSTR];     // h hi
  __shared__ f16 Hl[8][64 * LSTR];     // h lo
  __shared__ int sOrd[64], sLen[64];
  int tid = threadIdx.x;
  int r0 = blockIdx.x * 64;
  if (tid < 64) { sOrd[tid] = order[r0 + tid]; sLen[tid] = len_s[r0 + tid]; }
  for (int i = tid; i < 64 * 256; i += 512) {
    int row = i >> 8, k = i & 255;
    float v = h0[k];
    f16 hi = (f16)v;
    int idx = row * LSTR + (k & 31);
    Hh[k >> 5][idx] = hi;
    Hl[k >> 5][idx] = (f16)(v - (float)hi);
  }
  __syncthreads();
  int maxl = sLen[0];                 // sorted desc -> first row of stripe is max
  int lane = tid & 63, wid = tid >> 6;
  int quad = lane >> 4, mr = lane & 15;
  int jw = wid * 32;                  // this wave's 32 h-columns
  float br_[2], bz_[2], bxn_[2], bhn_[2];
  int wboff[2][3];                    // packed-layout fragment offsets
#pragma unroll
  for (int cf = 0; cf < 2; ++cf) {
    int j = jw + cf * 16 + mr;
    br_[cf]  = bih[j] + bhh[j];
    bz_[cf]  = bih[256 + j] + bhh[256 + j];
    bxn_[cf] = bih[512 + j];
    bhn_[cf] = bhh[512 + j];
    int jt = wid * 2 + cf;
#pragma unroll
    for (int g = 0; g < 3; ++g)
      wboff[cf][g] = (jt * 3 + g) * 512 + lane * 8;
  }
  // per-thread x element offsets (8 float4 = 64 rows x 64 col-groups / 512 thr)
  int xoff[8];
#pragma unroll
  for (int i = 0; i < 8; ++i) {
    int q = tid + 512 * i;
    int row = q >> 6, c4 = (q & 63) << 2;
    xoff[i] = sOrd[row] * (T_STEPS * H_DIM) + c4;
  }
  f32x4 xr[8];
#pragma unroll
  for (int i = 0; i < 8; ++i)         // prefetch t=0 (nontemporal, evict-first)
    xr[i] = __builtin_nontemporal_load(reinterpret_cast<const f32x4*>(&x[xoff[i]]));

  for (int t = 0; t < maxl; ++t) {
    __syncthreads();                  // prev epilogue H-writes done
    // commit prefetched x(t) regs -> LDS (f16)
#pragma unroll
    for (int i = 0; i < 8; ++i) {
      int q = tid + 512 * i;
      int row = q >> 6, c4 = (q & 63) << 2;
      f16x4 hx;
      hx[0] = (f16)xr[i][0]; hx[1] = (f16)xr[i][1];
      hx[2] = (f16)xr[i][2]; hx[3] = (f16)xr[i][3];
      *reinterpret_cast<f16x4*>(&Xs[c4 >> 5][row * LSTR + (c4 & 31)]) = hx;
    }
    __syncthreads();                  // Xs ready
    f32x4 accR[4][2] = {}, accZ[4][2] = {}, accXN[4][2] = {}, accHN[4][2] = {};
    // RUNTIME k-chunk loop: unroll disabled so only ONE iteration's weight
    // loads are in flight -> no register-pressure blowup, no scratch spills.
#pragma clang loop unroll(disable)
    for (int kt = 0; kt < 8; ++kt) {
      const f16* pih = wihp + kt * 24576;   // 16 jt * 3 g * 512
      const f16* phh = whhp + kt * 24576;
      f16x8 bf[12];                   // single-buffered weight frags (48 VGPR)
#pragma unroll
      for (int cf = 0; cf < 2; ++cf)
#pragma unroll
        for (int g = 0; g < 3; ++g) {
          bf[cf * 6 + g * 2 + 0] = *reinterpret_cast<const f16x8*>(&pih[wboff[cf][g]]);
          bf[cf * 6 + g * 2 + 1] = *reinterpret_cast<const f16x8*>(&phh[wboff[cf][g]]);
        }
#pragma unroll
      for (int im = 0; im < 4; ++im) {
        f16x8 ax = ld8lds(&Xs[kt][(im * 16 + mr) * LSTR + quad * 8]);
        f16x8 ah = ld8lds(&Hh[kt][(im * 16 + mr) * LSTR + quad * 8]);
        f16x8 al = ld8lds(&Hl[kt][(im * 16 + mr) * LSTR + quad * 8]);
#pragma unroll
        for (int cf = 0; cf < 2; ++cf) {
          accR[im][cf]  = __builtin_amdgcn_mfma_f32_16x16x32_f16(ax, bf[cf*6+0], accR[im][cf], 0, 0, 0);
          accR[im][cf]  = __builtin_amdgcn_mfma_f32_16x16x32_f16(ah, bf[cf*6+1], accR[im][cf], 0, 0, 0);
          accR[im][cf]  = __builtin_amdgcn_mfma_f32_16x16x32_f16(al, bf[cf*6+1], accR[im][cf], 0, 0, 0);
          accZ[im][cf]  = __builtin_amdgcn_mfma_f32_16x16x32_f16(ax, bf[cf*6+2], accZ[im][cf], 0, 0, 0);
          accZ[im][cf]  = __builtin_amdgcn_mfma_f32_16x16x32_f16(ah, bf[cf*6+3], accZ[im][cf], 0, 0, 0);
          accZ[im][cf]  = __builtin_amdgcn_mfma_f32_16x16x32_f16(al, bf[cf*6+3], accZ[im][cf], 0, 0, 0);
          accXN[im][cf] = __builtin_amdgcn_mfma_f32_16x16x32_f16(ax, bf[cf*6+4], accXN[im][cf], 0, 0, 0);
          accHN[im][cf] = __builtin_amdgcn_mfma_f32_16x16x32_f16(ah, bf[cf*6+5], accHN[im][cf], 0, 0, 0);
          accHN[im][cf] = __builtin_amdgcn_mfma_f32_16x16x32_f16(al, bf[cf*6+5], accHN[im][cf], 0, 0, 0);
        }
      }
    }
    if (t + 1 < maxl) {
      // x(t+1) prefetch: issued after all weight loads; HBM latency hides
      // under the epilogue (transcendentals) + barriers + next-step staging.
#pragma unroll
      for (int i = 0; i < 8; ++i)
        xr[i] = __builtin_nontemporal_load(
            reinterpret_cast<const f32x4*>(&x[xoff[i] + (t + 1) * H_DIM]));
    }
    __syncthreads();                  // all waves' H reads done before H rewrite
    // epilogue: GRU cell. C/D layout: col=mr, row=quad*4+reg.
#pragma unroll
    for (int im = 0; im < 4; ++im)
#pragma unroll
      for (int cf = 0; cf < 2; ++cf)
#pragma unroll
        for (int r = 0; r < 4; ++r) {
          int m = im * 16 + quad * 4 + r;
          int idx = m * LSTR + cf * 16 + mr;   // chunk = wid (j>>5), kk = j&31
          float rg = 1.0f / (1.0f + expf(-(accR[im][cf][r] + br_[cf])));
          float zg = 1.0f / (1.0f + expf(-(accZ[im][cf][r] + bz_[cf])));
          float ng = tanhf(accXN[im][cf][r] + bxn_[cf] + rg * (accHN[im][cf][r] + bhn_[cf]));
          float hp = (float)Hh[wid][idx] + (float)Hl[wid][idx];
          float hv = (1.0f - zg) * ng + zg * hp;
          f16 hi = (f16)hv;
          Hh[wid][idx] = hi;
          Hl[wid][idx] = (f16)(hv - (float)hi);
          if (t == sLen[m] - 1)
            last[(size_t)sOrd[m] * H_DIM + (jw + cf * 16 + mr)] = hv;
        }
  }
}

// ------------------------------------------------------------------
// 128x128 f16 MFMA GEMM, B always pre-split f16 [N,K] (B0=hi, B1=lo).
// AMODE 0: A f32 [M,K], on-the-fly hi/lo split.
// AMODE 1: A = bitmask (u32 words, K/32 per row) -> 0/1 f16.
// AMODE 2: A pre-split f16 [M,K] hi/lo (Ahi/Alo).
// NTERMS: 1 = Ah*Bh; 2 = +Al*Bh; 3 = +Ah*Bl.
// EPI: 0 store C f32; 1 threshold->bitmask (ballot); 2 store C*scale_m[m];
//      3 atomicAdd C += v*scale_m[m].
// SYMM (EPI=1): grid is triangular (skip by>bx); off-diag blocks also write
// the transposed bitmask chunk via ballot-transpose.
template<int AMODE, int NTERMS, int EPI, int SYMM>
__global__ __launch_bounds__(256)
void k_gemm(const float* __restrict__ A, const f16* __restrict__ Ahi,
            const f16* __restrict__ Alo, const u32* __restrict__ Abits,
            const f16* __restrict__ B0, const f16* __restrict__ B1,
            float* __restrict__ C, u16* __restrict__ bitsOut,
            const float* __restrict__ scale_m, const float* __restrict__ phi_p,
            int M, int Nn, int K, int kLen) {
  int bx = blockIdx.x, by = blockIdx.y;
  if (SYMM && by > bx) return;
  int n0 = bx * 128, m0 = by * 128;
  int kStart = blockIdx.z * kLen;
  constexpr int SB = 128 * LSTR;
  constexpr int NBUF = (NTERMS == 3) ? 4 : ((NTERMS == 2) ? 3 : 2);
  __shared__ f16 smem[SB * NBUF];
  f16* Ah = smem;
  f16* Bh = smem + SB;
  f16* Al = smem + 2 * SB;   // valid iff NTERMS>=2
  f16* Bl = smem + 3 * SB;   // valid iff NTERMS==3
  int tid = threadIdx.x;
  int lane = tid & 63, wid = tid >> 6;
  int wm = wid & 1, wn = wid >> 1;
  int quad = lane >> 4, mr = lane & 15;
  f32x4 acc[4][4] = {};
  const int nkt = kLen >> 5;
  for (int kt = 0; kt < nkt; ++kt) {
    int kg = kStart + (kt << 5);
    if (AMODE == 0) {
#pragma unroll
      for (int i = 0; i < 4; ++i) {
        int q = tid + 256 * i;          // 1024 float4: 128 rows x 8
        int row = q >> 3, kc = (q & 7) << 2;
        float4 v = *reinterpret_cast<const float4*>(&A[(size_t)(m0 + row) * K + kg + kc]);
        f16 h0_ = (f16)v.x, h1_ = (f16)v.y, h2_ = (f16)v.z, h3_ = (f16)v.w;
        f16x4 hh; hh[0] = h0_; hh[1] = h1_; hh[2] = h2_; hh[3] = h3_;
        *reinterpret_cast<f16x4*>(&Ah[row * LSTR + kc]) = hh;
        if (NTERMS >= 2) {
          f16x4 hl;
          hl[0] = (f16)(v.x - (float)h0_); hl[1] = (f16)(v.y - (float)h1_);
          hl[2] = (f16)(v.z - (float)h2_); hl[3] = (f16)(v.w - (float)h3_);
          *reinterpret_cast<f16x4*>(&Al[row * LSTR + kc]) = hl;
        }
      }
    } else if (AMODE == 2) {
#pragma unroll
      for (int i = 0; i < 2; ++i) {
        int c = tid + 256 * i;          // 512 chunks of 8 f16
        int row = c >> 2, kc = (c & 3) << 3;
        f16x8 v = *reinterpret_cast<const f16x8*>(&Ahi[(size_t)(m0 + row) * K + kg + kc]);
        st8lds(&Ah[row * LSTR + kc], v);
        if (NTERMS >= 2) {
          f16x8 v2 = *reinterpret_cast<const f16x8*>(&Alo[(size_t)(m0 + row) * K + kg + kc]);
          st8lds(&Al[row * LSTR + kc], v2);
        }
      }
    } else {
      if (tid < 128) {
        int row = tid;
        u32 w = Abits[(size_t)(m0 + row) * (K >> 5) + (kg >> 5)];
        u32* dst = reinterpret_cast<u32*>(&Ah[row * LSTR]);
#pragma unroll
        for (int p = 0; p < 16; ++p) {
          union { f16 h[2]; u32 u; } pk;
          pk.h[0] = ((w >> (2 * p)) & 1u) ? (f16)1.0f : (f16)0.0f;
          pk.h[1] = ((w >> (2 * p + 1)) & 1u) ? (f16)1.0f : (f16)0.0f;
          dst[p] = pk.u;
        }
      }
    }
    // B stage: pre-split f16 [N,K]
#pragma unroll
    for (int i = 0; i < 2; ++i) {
      int c = tid + 256 * i;            // 512 chunks of 8 f16
      int row = c >> 2, kc = (c & 3) << 3;
      f16x8 v = *reinterpret_cast<const f16x8*>(&B0[(size_t)(n0 + row) * K + kg + kc]);
      st8lds(&Bh[row * LSTR + kc], v);
      if (NTERMS == 3) {
        f16x8 v2 = *reinterpret_cast<const f16x8*>(&B1[(size_t)(n0 + row) * K + kg + kc]);
        st8lds(&Bl[row * LSTR + kc], v2);
      }
    }
    __syncthreads();
    f16x8 af[4], bf[4], alr[4], blr[4];
#pragma unroll
    for (int im = 0; im < 4; ++im) {
      af[im] = ld8lds(&Ah[(wm * 64 + im * 16 + mr) * LSTR + quad * 8]);
      if (NTERMS >= 2)
        alr[im] = ld8lds(&Al[(wm * 64 + im * 16 + mr) * LSTR + quad * 8]);
    }
#pragma unroll
    for (int in = 0; in < 4; ++in) {
      bf[in] = ld8lds(&Bh[(wn * 64 + in * 16 + mr) * LSTR + quad * 8]);
      if (NTERMS == 3)
        blr[in] = ld8lds(&Bl[(wn * 64 + in * 16 + mr) * LSTR + quad * 8]);
    }
#pragma unroll
    for (int im = 0; im < 4; ++im)
#pragma unroll
      for (int in = 0; in < 4; ++in) {
        acc[im][in] = __builtin_amdgcn_mfma_f32_16x16x32_f16(af[im], bf[in], acc[im][in], 0, 0, 0);
        if (NTERMS >= 2)
          acc[im][in] = __builtin_amdgcn_mfma_f32_16x16x32_f16(alr[im], bf[in], acc[im][in], 0, 0, 0);
        if (NTERMS == 3)
          acc[im][in] = __builtin_amdgcn_mfma_f32_16x16x32_f16(af[im], blr[in], acc[im][in], 0, 0, 0);
      }
    __syncthreads();
  }
  float phiK = 0.0f;
  if (EPI == 1) phiK = phi_p[0] * 65536.0f;   // dot/65536 >= phi  <=>  dot >= phi*65536 (exact, pow2)
#pragma unroll
  for (int im = 0; im < 4; ++im) {
#pragma unroll
    for (int in = 0; in < 4; ++in) {
      int nn = n0 + wn * 64 + in * 16 + mr;
      int mb = m0 + wm * 64 + im * 16 + quad * 4;
      if (EPI == 1) {
        u64 bal[4];
#pragma unroll
        for (int r = 0; r < 4; ++r) {
          int m = mb + r;
          bool one = (acc[im][in][r] >= phiK) || (m == nn);   // diag forced to 1
          bal[r] = __ballot(one);
        }
#pragma unroll
        for (int r = 0; r < 4; ++r) {
          if (mr == 0) {
            u16 chunk = (u16)((bal[r] >> (16 * quad)) & 0xFFFFu);
            bitsOut[(size_t)(mb + r) * (Nn >> 4) + (nn >> 4)] = chunk;
          }
        }
        if (SYMM && m0 != n0) {
          // transposed chunk: row nn (by mr), 16 m-bits j=quad'*4+r'
          u32 tb = 0;
#pragma unroll
          for (int jb = 0; jb < 16; ++jb)
            tb |= (u32)((bal[jb & 3] >> ((jb >> 2) * 16 + mr)) & 1ull) << jb;
          if (quad == 0) {
            int nnr = n0 + wn * 64 + in * 16 + mr;
            int mch = (m0 + wm * 64 + im * 16) >> 4;
            bitsOut[(size_t)nnr * (Nn >> 4) + mch] = (u16)tb;
          }
        }
      } else {
#pragma unroll
        for (int r = 0; r < 4; ++r) {
          int m = mb + r;
          float v = acc[im][in][r];
          if (EPI == 0) {
            C[(size_t)m * Nn + nn] = v;
          } else if (EPI == 2) {
            C[(size_t)m * Nn + nn] = v * scale_m[m];
          } else {
            atomicAdd(&C[(size_t)m * Nn + nn], v * scale_m[m]);
          }
        }
      }
    }
  }
}

// ------------------------------------------------------------------
__global__ void k_split16(const float* __restrict__ src, f16* __restrict__ hi,
                          f16* __restrict__ lo) {
  int i = blockIdx.x * 256 + threadIdx.x;   // N*H
  float v = src[i];
  f16 h = (f16)v;
  hi[i] = h; lo[i] = (f16)(v - (float)h);
}

__global__ void k_degdis(const u32* __restrict__ bits, float* __restrict__ dis) {
  __shared__ int red[4];
  int row = blockIdx.x, tid = threadIdx.x;
  u32 w = bits[(size_t)row * 256 + tid];
  int c = __popc(w);
  for (int off = 32; off > 0; off >>= 1) c += __shfl_down(c, off);
  if ((tid & 63) == 0) red[tid >> 6] = c;
  __syncthreads();
  if (tid == 0) {
    int s = red[0] + red[1] + red[2] + red[3];
    dis[row] = s > 0 ? rsqrtf((float)s) : 0.0f;
  }
}

__global__ void k_outinit(const float* __restrict__ b, float* __restrict__ out) {
  int i = blockIdx.x * 256 + threadIdx.x;
  out[i] = b[i & (H_DIM - 1)];
}

// ------------------------------------------------------------------
extern "C" void kernel_launch(void* const* d_in, const int* in_sizes, int n_in,
                              void* d_out, int out_size, void* d_ws, size_t ws_size,
                              hipStream_t stream) {
  (void)in_sizes; (void)n_in; (void)out_size; (void)ws_size;
  const float* x    = (const float*)d_in[0];
  const int*   he   = (const int*)d_in[1];
  const int*   slen = (const int*)d_in[2];
  const float* h0   = (const float*)d_in[3];
  const float* wih  = (const float*)d_in[4];
  const float* whh  = (const float*)d_in[5];
  const float* bih  = (const float*)d_in[6];
  const float* bhh  = (const float*)d_in[7];
  const float* hw[3] = {(const float*)d_in[8], (const float*)d_in[10], (const float*)d_in[12]};
  const float* hb[3] = {(const float*)d_in[9], (const float*)d_in[11], (const float*)d_in[13]};
  const float* phi  = (const float*)d_in[14];
  const float* gw   = (const float*)d_in[15];
  const float* gb   = (const float*)d_in[16];
  float* out = (float*)d_out;

  // ---- workspace layout, everything re-initialized every call ----
  size_t off = 0;
  char* wsb = (char*)d_ws;
  auto alloc = [&](size_t b) { void* p = wsb + off; off += (b + 255) & ~(size_t)255; return p; };
  int*   order = (int*)alloc(N_NODES * 4);
  int*   lens  = (int*)alloc(N_NODES * 4);
  int*   Mts   = (int*)alloc(256);
  u32*   histD = (u32*)alloc(N_NODES * 4);
  u32*   histB = (u32*)alloc(N_EDGES * 4);
  float* dinv  = (float*)alloc(N_NODES * 4);
  float* binv  = (float*)alloc(N_EDGES * 4);
  float* dis   = (float*)alloc(N_NODES * 4);
  int*   noff  = (int*)alloc((N_NODES + 1) * 4);
  int*   eoff  = (int*)alloc((N_EDGES + 1) * 4);
  int*   ncur  = (int*)alloc(N_NODES * 4);
  int*   ecur  = (int*)alloc(N_EDGES * 4);
  int*   nlist = (int*)alloc(NNZ_ * 4);
  int*   elist = (int*)alloc(NNZ_ * 4);
  f16*   wihp  = (f16*)alloc(768 * 256 * 2);   // packed fragment-order weights
  f16*   whhp  = (f16*)alloc(768 * 256 * 2);
  f16*   hwT[3]; f16* hwTlo[3];
  for (int c = 0; c < 3; ++c) {
    hwT[c]   = (f16*)alloc(256 * 256 * 2);
    hwTlo[c] = (f16*)alloc(256 * 256 * 2);
  }
  f16*   gwT   = (f16*)alloc(256 * 256 * 2);
  f16*   gwTlo = (f16*)alloc(256 * 256 * 2);
  float* oA    = (float*)alloc((size_t)N_NODES * H_DIM * 4);   // `last`, then o2
  float* oB    = (float*)alloc((size_t)N_NODES * H_DIM * 4);   // o1, then o3
  float* xwb   = (float*)alloc((size_t)N_NODES * H_DIM * 4);   // xw scratch / z
  float* eb    = (float*)alloc((size_t)N_EDGES * H_DIM * 4);
  f16*   o3hi  = (f16*)alloc((size_t)N_NODES * H_DIM * 2);
  f16*   o3lo  = (f16*)alloc((size_t)N_NODES * H_DIM * 2);
  f16*   z16T  = (f16*)alloc((size_t)H_DIM * N_NODES * 2);     // z^T [256][8192]
  u32*   Abits = (u32*)alloc((size_t)N_NODES * 256 * 4);       // 8192x8192 bits

  // ---- preprocessing ----
  k_sort<<<1, 256, 0, stream>>>(slen, order, lens, Mts);
  k_wpack<<<768, 256, 0, stream>>>(wih, whh, wihp, whhp);
  hipMemsetAsync(histD, 0, N_NODES * 4, stream);
  hipMemsetAsync(histB, 0, N_EDGES * 4, stream);
  k_hist<<<NNZ_ / 256, 256, 0, stream>>>(he, histD, histB);
  k_inv<<<N_NODES / 256, 256, 0, stream>>>(histD, histB, dinv, binv);
  k_scan<<<1, 256, 0, stream>>>(histD, histB, noff, eoff, ncur, ecur);
  k_fill<<<NNZ_ / 256, 256, 0, stream>>>(he, ncur, ecur, nlist, elist);
  for (int c = 0; c < 3; ++c)
    k_tsplit<<<dim3(4, 4), 256, 0, stream>>>(hw[c], hwT[c], hwTlo[c], 256, 256, 1);
  k_tsplit<<<dim3(4, 4), 256, 0, stream>>>(gw, gwT, gwTlo, 256, 256, 1);

  // ---- GRU: ONE persistent launch, all 32 steps, h resident in LDS ----
  k_gru_all<<<N_NODES / 64, 512, 0, stream>>>(x, h0, oA, wihp, whhp,
                                              bih, bhh, order, lens);
  // oA now holds `last` in original node order.

  // ---- 3x HypergraphConv with residual (CSR gather, no atomics) ----
  float* prev = oA; float* nxt = oB;
  for (int c = 0; c < 3; ++c) {
    k_gemm<0, 3, 0, 0><<<dim3(2, 64, 1), 256, 0, stream>>>(
        prev, nullptr, nullptr, nullptr, hwT[c], hwTlo[c], xwb, nullptr,
        nullptr, nullptr, N_NODES, H_DIM, H_DIM, H_DIM);
    k_edge_gather<<<N_EDGES, 256, 0, stream>>>(xwb, eoff, nlist, binv, eb);
    k_node_gather<<<N_NODES, 256, 0, stream>>>(eb, noff, elist, dinv, prev, hb[c], nxt);
    float* tmp = prev; prev = nxt; nxt = tmp;
  }
  float* o3 = prev;  // == oB after 3 swaps

  // ---- dynamic adjacency: gram -> bitmask (triangular + mirrored), degrees ----
  k_split16<<<N_NODES, 256, 0, stream>>>(o3, o3hi, o3lo);
  k_gemm<2, 3, 1, 1><<<dim3(64, 64, 1), 256, 0, stream>>>(
      nullptr, o3hi, o3lo, nullptr, o3hi, o3lo, nullptr, (u16*)Abits,
      nullptr, phi, N_NODES, N_NODES, H_DIM, H_DIM);
  k_degdis<<<N_NODES, 256, 0, stream>>>(Abits, dis);

  // ---- z = dis .* (o3 @ gcn_w), then transpose-split to z16T ----
  k_gemm<2, 3, 2, 0><<<dim3(2, 64, 1), 256, 0, stream>>>(
      nullptr, o3hi, o3lo, nullptr, gwT, gwTlo, xwb, nullptr,
      dis, nullptr, N_NODES, H_DIM, H_DIM, H_DIM);
  k_tsplit<<<dim3(128, 4), 256, 0, stream>>>(xwb, z16T, nullptr, N_NODES, H_DIM, 0);

  // ---- out = dis .* (A @ z) + gcn_b  (bitmask A in LDS, split-K=4) ----
  k_outinit<<<N_NODES, 256, 0, stream>>>(gb, out);
  k_gemm<1, 1, 3, 0><<<dim3(2, 64, 4), 256, 0, stream>>>(
      nullptr, nullptr, nullptr, Abits, z16T, nullptr, out, nullptr,
      dis, nullptr, N_NODES, H_DIM, N_NODES, N_NODES / 4);
}

// Round 6
// 1309.494 us; speedup vs baseline: 1.3218x; 1.3218x over previous
//
#include <hip/hip_runtime.h>
#include <cstdint>
#include <cstddef>

typedef _Float16 f16;
typedef __attribute__((ext_vector_type(4))) _Float16 f16x4;
typedef __attribute__((ext_vector_type(8))) _Float16 f16x8;
typedef __attribute__((ext_vector_type(4))) float f32x4;
typedef uint32_t u32;
typedef uint16_t u16;
typedef unsigned long long u64;

#define N_NODES 8192
#define T_STEPS 32
#define H_DIM   256
#define N_EDGES 1024
#define NNZ_    65536

// LDS row stride: 36 f16 = 18 words; mr*18 mod 32 has 16 distinct residues
// -> conflict-free fragment reads (vs 40 f16 = 20 words, period 8, 2-4x conflicts).
#define LSTR 36

__device__ __forceinline__ f16x8 ld8lds(const f16* p) {
  union { f16x8 v8; f16x4 v4[2]; } u;
  u.v4[0] = *reinterpret_cast<const f16x4*>(p);
  u.v4[1] = *reinterpret_cast<const f16x4*>(p + 4);
  return u.v8;
}
__device__ __forceinline__ void st8lds(f16* p, f16x8 v) {
  union { f16x8 v8; f16x4 v4[2]; } u; u.v8 = v;
  *reinterpret_cast<f16x4*>(p) = u.v4[0];
  *reinterpret_cast<f16x4*>(p + 4) = u.v4[1];
}

// ------------------------------------------------------------------
// counting sort of nodes by length, descending. Also emits M_t = #{len>t}.
__global__ void k_sort(const int* __restrict__ len, int* __restrict__ order,
                       int* __restrict__ len_s, int* __restrict__ Mts) {
  __shared__ int hist[33];
  __shared__ int cur[33];
  int tid = threadIdx.x;
  if (tid < 33) hist[tid] = 0;
  __syncthreads();
  for (int i = tid; i < N_NODES; i += 256) {
    int l = len[i]; l = l < 0 ? 0 : (l > 32 ? 32 : l);
    atomicAdd(&hist[l], 1);
  }
  __syncthreads();
  if (tid == 0) {
    int acc = 0;
    for (int l = 32; l >= 0; --l) { cur[l] = acc; acc += hist[l]; }
    for (int t = 0; t < 32; ++t) Mts[t] = cur[t];  // cur[t] = #{len > t}
  }
  __syncthreads();
  for (int i = tid; i < N_NODES; i += 256) {
    int l = len[i]; l = l < 0 ? 0 : (l > 32 ? 32 : l);
    int pos = atomicAdd(&cur[l], 1);
    order[pos] = i; len_s[pos] = l;
  }
}

// Pack GRU weights into MFMA-fragment order so fragment loads are fully
// coalesced (lane-contiguous). Packed layout, per matrix (wih / whh):
//   tile = (kt*16 + jt)*3 + g          (384 tiles of 512 f16 = 1 KB)
//   within-tile offset = (quad*16 + mr)*8 + e  = lane*8 + e
//   source element = W[g*256 + jt*16 + mr][kt*32 + quad*8 + e]
// A wave's fragment load (fixed kt, jt, g) is then base + lane*16B ->
// one contiguous 1 KB read (8 fully-used 128B lines) instead of 64
// partially-used lines (the round-4 L2-amplification bottleneck).
__global__ void k_wpack(const float* __restrict__ wih, const float* __restrict__ whh,
                        f16* __restrict__ wihp, f16* __restrict__ whhp) {
  int i = blockIdx.x * 256 + threadIdx.x;        // 768*256 = 196608 elems
  int tile = i >> 9, within = i & 511;
  int quad = within >> 7, mr = (within >> 3) & 15, e = within & 7;
  int g = tile % 3, t3 = tile / 3;
  int jt = t3 & 15, kt = t3 >> 4;
  int row = g * 256 + jt * 16 + mr;
  int col = kt * 32 + quad * 8 + e;
  wihp[i] = (f16)wih[row * 256 + col];
  whhp[i] = (f16)whh[row * 256 + col];
}

__global__ void k_hist(const int* __restrict__ he, u32* __restrict__ hd, u32* __restrict__ hb) {
  int i = blockIdx.x * 256 + threadIdx.x;
  if (i < NNZ_) {
    atomicAdd(&hd[he[i]], 1u);
    atomicAdd(&hb[he[NNZ_ + i]], 1u);
  }
}

__global__ void k_inv(const u32* __restrict__ hd, const u32* __restrict__ hb,
                      float* __restrict__ dinv, float* __restrict__ binv) {
  int i = blockIdx.x * 256 + threadIdx.x;
  if (i < N_NODES) dinv[i] = hd[i] ? 1.0f / (float)hd[i] : 0.0f;
  if (i < N_EDGES) binv[i] = hb[i] ? 1.0f / (float)hb[i] : 0.0f;
}

// ------------------------------------------------------------------
// Exclusive prefix scan of node/edge histograms -> CSR offsets + cursors.
__global__ void k_scan(const u32* __restrict__ histD, const u32* __restrict__ histB,
                       int* __restrict__ noff, int* __restrict__ eoff,
                       int* __restrict__ ncur, int* __restrict__ ecur) {
  __shared__ int buf[256];
  __shared__ int base;
  int tid = threadIdx.x;
  if (tid == 0) base = 0;
  __syncthreads();
  for (int ch = 0; ch < N_NODES / 256; ++ch) {
    int i = ch * 256 + tid;
    int v = (int)histD[i];
    buf[tid] = v; __syncthreads();
    for (int off = 1; off < 256; off <<= 1) {
      int t = (tid >= off) ? buf[tid - off] : 0; __syncthreads();
      buf[tid] += t; __syncthreads();
    }
    int excl = base + buf[tid] - v;
    noff[i] = excl; ncur[i] = excl;
    __syncthreads();
    if (tid == 255) { base += buf[255]; if (i == N_NODES - 1) noff[N_NODES] = base; }
    __syncthreads();
  }
  if (tid == 0) base = 0;
  __syncthreads();
  for (int ch = 0; ch < N_EDGES / 256; ++ch) {
    int i = ch * 256 + tid;
    int v = (int)histB[i];
    buf[tid] = v; __syncthreads();
    for (int off = 1; off < 256; off <<= 1) {
      int t = (tid >= off) ? buf[tid - off] : 0; __syncthreads();
      buf[tid] += t; __syncthreads();
    }
    int excl = base + buf[tid] - v;
    eoff[i] = excl; ecur[i] = excl;
    __syncthreads();
    if (tid == 255) { base += buf[255]; if (i == N_EDGES - 1) eoff[N_EDGES] = base; }
    __syncthreads();
  }
}

__global__ void k_fill(const int* __restrict__ he, int* __restrict__ ncur,
                       int* __restrict__ ecur, int* __restrict__ nlist,
                       int* __restrict__ elist) {
  int i = blockIdx.x * 256 + threadIdx.x;
  if (i < NNZ_) {
    int node = he[i], edge = he[NNZ_ + i];
    int p1 = atomicAdd(&ecur[edge], 1); nlist[p1] = node;  // per-edge node list
    int p2 = atomicAdd(&ncur[node], 1); elist[p2] = edge;  // per-node edge list
  }
}

// e[edge][c] = Binv[edge] * sum_{node in edge} xw[node][c]   (gather, no atomics)
__global__ __launch_bounds__(256)
void k_edge_gather(const float* __restrict__ xw, const int* __restrict__ eoff,
                   const int* __restrict__ nlist, const float* __restrict__ binv,
                   float* __restrict__ e) {
  int edge = blockIdx.x, c = threadIdx.x;
  int s = eoff[edge], t = eoff[edge + 1];
  __shared__ int nds[256];
  float sum = 0.0f;
  for (int base = s; base < t; base += 256) {
    int nchunk = t - base; if (nchunk > 256) nchunk = 256;
    if (c < nchunk) nds[c] = nlist[base + c];
    __syncthreads();
    for (int k = 0; k < nchunk; ++k)
      sum += xw[(size_t)nds[k] * H_DIM + c];
    __syncthreads();
  }
  e[(size_t)edge * H_DIM + c] = sum * binv[edge];
}

// out[node][c] = prev[node][c] + bias[c] + Dinv[node] * sum_{edge in node} e[edge][c]
__global__ __launch_bounds__(256)
void k_node_gather(const float* __restrict__ e, const int* __restrict__ noff,
                   const int* __restrict__ elist, const float* __restrict__ dinv,
                   const float* __restrict__ prev, const float* __restrict__ bias,
                   float* __restrict__ outp) {
  int node = blockIdx.x, c = threadIdx.x;
  int s = noff[node], t = noff[node + 1];
  __shared__ int eds[64];
  float sum = 0.0f;
  for (int base = s; base < t; base += 64) {
    int nchunk = t - base; if (nchunk > 64) nchunk = 64;
    if (c < nchunk) eds[c] = elist[base + c];
    __syncthreads();
    for (int k = 0; k < nchunk; ++k)
      sum += e[(size_t)eds[k] * H_DIM + c];
    __syncthreads();
  }
  outp[(size_t)node * H_DIM + c] =
      prev[(size_t)node * H_DIM + c] + bias[c] + dinv[node] * sum;
}

// ------------------------------------------------------------------
// Transpose + f16 hi/lo split: src [Mp][Np] f32 -> hiT/loT [Np][Mp] f16.
__global__ __launch_bounds__(256)
void k_tsplit(const float* __restrict__ src, f16* __restrict__ hiT,
              f16* __restrict__ loT, int Mp, int Np, int withLo) {
  __shared__ float tile[64][65];
  int m0 = blockIdx.x * 64, n0 = blockIdx.y * 64;
  int tid = threadIdx.x;
#pragma unroll
  for (int i = 0; i < 4; ++i) {
    int q = tid + 256 * i;             // 1024 float4 = 64 rows x 64 cols
    int row = q >> 4, c4 = (q & 15) << 2;
    float4 v = *reinterpret_cast<const float4*>(&src[(size_t)(m0 + row) * Np + n0 + c4]);
    tile[row][c4] = v.x; tile[row][c4 + 1] = v.y;
    tile[row][c4 + 2] = v.z; tile[row][c4 + 3] = v.w;
  }
  __syncthreads();
#pragma unroll
  for (int i = 0; i < 4; ++i) {
    int q = tid + 256 * i;
    int nrow = q >> 4, mc = (q & 15) << 2;
    f16x4 h, l;
#pragma unroll
    for (int j = 0; j < 4; ++j) {
      float v = tile[mc + j][nrow];
      h[j] = (f16)v;
      l[j] = (f16)(v - (float)h[j]);
    }
    *reinterpret_cast<f16x4*>(&hiT[(size_t)(n0 + nrow) * Mp + m0 + mc]) = h;
    if (withLo)
      *reinterpret_cast<f16x4*>(&loT[(size_t)(n0 + nrow) * Mp + m0 + mc]) = l;
  }
}

// ------------------------------------------------------------------
// Persistent GRU: ONE launch for all 32 time steps.
// Round-6 = proven pieces combined:
//  - 256 blocks x 32 rows x 512 thr (r4: all CUs busy, spill-free VGPR 104,
//    2 blocks/CU -> 4 waves/SIMD TLP hides single-buffered weight latency).
//  - Packed fragment-order weights (r5: lane-contiguous 1 KB wave-loads,
//    2x better per-work vs strided).
//  - NEW: Xs double-buffered -> 2 barriers/step (was 3). The serial
//    {barrier; x-commit; barrier} region is gone: x(t+1) loads issue after
//    the compute phase and are committed to Xs[cur^1] at the END of the
//    epilogue (>=2000 cyc later, HBM latency fully hidden), covered by the
//    step's closing barrier. LDS 74 KB -> still 2 blocks/CU.
//  - launch_bounds(512,4): cap VGPR at 128 to guarantee 4 waves/SIMD.
__global__ __launch_bounds__(512, 4)
void k_gru_all(const float* __restrict__ x, const float* __restrict__ h0,
               float* __restrict__ last,
               const f16* __restrict__ wihp, const f16* __restrict__ whhp,
               const float* __restrict__ bih, const float* __restrict__ bhh,
               const int* __restrict__ order, const int* __restrict__ len_s) {
  __shared__ f16 Xs[2][8][32 * LSTR];  // x tile, double-buffered (cur = t&1)
  __shared__ f16 Hh[8][32 * LSTR];     // h hi
  __shared__ f16 Hl[8][32 * LSTR];     // h lo
  __shared__ int sOrd[32], sLen[32];
  int tid = threadIdx.x;
  int r0 = blockIdx.x * 32;
  if (tid < 32) { sOrd[tid] = order[r0 + tid]; sLen[tid] = len_s[r0 + tid]; }
  for (int i = tid; i < 32 * 256; i += 512) {
    int row = i >> 8, k = i & 255;
    float v = h0[k];
    f16 hi = (f16)v;
    int idx = row * LSTR + (k & 31);
    Hh[k >> 5][idx] = hi;
    Hl[k >> 5][idx] = (f16)(v - (float)hi);
  }
  __syncthreads();                    // sOrd ready (for xoff below)
  int maxl = sLen[0];                 // sorted desc -> first row of stripe is max
  int lane = tid & 63, wid = tid >> 6;
  int quad = lane >> 4, mr = lane & 15;
  int jw = wid * 32;                  // this wave's 32 h-columns
  float br_[2], bz_[2], bxn_[2], bhn_[2];
  int wboff[2][3];                    // packed-layout fragment offsets
#pragma unroll
  for (int cf = 0; cf < 2; ++cf) {
    int j = jw + cf * 16 + mr;
    br_[cf]  = bih[j] + bhh[j];
    bz_[cf]  = bih[256 + j] + bhh[256 + j];
    bxn_[cf] = bih[512 + j];
    bhn_[cf] = bhh[512 + j];
    int jt = wid * 2 + cf;
#pragma unroll
    for (int g = 0; g < 3; ++g)
      wboff[cf][g] = (jt * 3 + g) * 512 + lane * 8;
  }
  // per-thread x element offsets (4 float4 = 32 rows x 64 col-groups / 512 thr)
  int xoff[4], xrow4[4], xc44[4];
#pragma unroll
  for (int i = 0; i < 4; ++i) {
    int q = tid + 512 * i;
    xrow4[i] = q >> 6; xc44[i] = (q & 63) << 2;
    xoff[i] = sOrd[xrow4[i]] * (T_STEPS * H_DIM) + xc44[i];
  }
  f32x4 xr[4];
#pragma unroll
  for (int i = 0; i < 4; ++i)         // load t=0 (nontemporal, evict-first)
    xr[i] = __builtin_nontemporal_load(reinterpret_cast<const f32x4*>(&x[xoff[i]]));
  // commit x(0) -> Xs[0]
#pragma unroll
  for (int i = 0; i < 4; ++i) {
    f16x4 hx;
    hx[0] = (f16)xr[i][0]; hx[1] = (f16)xr[i][1];
    hx[2] = (f16)xr[i][2]; hx[3] = (f16)xr[i][3];
    *reinterpret_cast<f16x4*>(&Xs[0][xc44[i] >> 5][xrow4[i] * LSTR + (xc44[i] & 31)]) = hx;
  }
  __syncthreads();                    // H init + Xs[0] visible

  for (int t = 0; t < maxl; ++t) {
    int cur = t & 1;
    f32x4 accR[2][2] = {}, accZ[2][2] = {}, accXN[2][2] = {}, accHN[2][2] = {};
    // RUNTIME k-chunk loop: unroll disabled so only ONE iteration's weight
    // loads are in flight -> no register-pressure blowup, no scratch spills.
#pragma clang loop unroll(disable)
    for (int kt = 0; kt < 8; ++kt) {
      const f16* pih = wihp + kt * 24576;   // 16 jt * 3 g * 512
      const f16* phh = whhp + kt * 24576;
      f16x8 bf[12];                   // single-buffered weight frags (48 VGPR)
#pragma unroll
      for (int cf = 0; cf < 2; ++cf)
#pragma unroll
        for (int g = 0; g < 3; ++g) {
          bf[cf * 6 + g * 2 + 0] = *reinterpret_cast<const f16x8*>(&pih[wboff[cf][g]]);
          bf[cf * 6 + g * 2 + 1] = *reinterpret_cast<const f16x8*>(&phh[wboff[cf][g]]);
        }
#pragma unroll
      for (int im = 0; im < 2; ++im) {
        f16x8 ax = ld8lds(&Xs[cur][kt][(im * 16 + mr) * LSTR + quad * 8]);
        f16x8 ah = ld8lds(&Hh[kt][(im * 16 + mr) * LSTR + quad * 8]);
        f16x8 al = ld8lds(&Hl[kt][(im * 16 + mr) * LSTR + quad * 8]);
#pragma unroll
        for (int cf = 0; cf < 2; ++cf) {
          accR[im][cf]  = __builtin_amdgcn_mfma_f32_16x16x32_f16(ax, bf[cf*6+0], accR[im][cf], 0, 0, 0);
          accR[im][cf]  = __builtin_amdgcn_mfma_f32_16x16x32_f16(ah, bf[cf*6+1], accR[im][cf], 0, 0, 0);
          accR[im][cf]  = __builtin_amdgcn_mfma_f32_16x16x32_f16(al, bf[cf*6+1], accR[im][cf], 0, 0, 0);
          accZ[im][cf]  = __builtin_amdgcn_mfma_f32_16x16x32_f16(ax, bf[cf*6+2], accZ[im][cf], 0, 0, 0);
          accZ[im][cf]  = __builtin_amdgcn_mfma_f32_16x16x32_f16(ah, bf[cf*6+3], accZ[im][cf], 0, 0, 0);
          accZ[im][cf]  = __builtin_amdgcn_mfma_f32_16x16x32_f16(al, bf[cf*6+3], accZ[im][cf], 0, 0, 0);
          accXN[im][cf] = __builtin_amdgcn_mfma_f32_16x16x32_f16(ax, bf[cf*6+4], accXN[im][cf], 0, 0, 0);
          accHN[im][cf] = __builtin_amdgcn_mfma_f32_16x16x32_f16(ah, bf[cf*6+5], accHN[im][cf], 0, 0, 0);
          accHN[im][cf] = __builtin_amdgcn_mfma_f32_16x16x32_f16(al, bf[cf*6+5], accHN[im][cf], 0, 0, 0);
        }
      }
    }
    if (t + 1 < maxl) {
      // issue x(t+1) loads now; committed at END of epilogue (~2000+ cyc
      // later) so HBM latency is fully hidden.
#pragma unroll
      for (int i = 0; i < 4; ++i)
        xr[i] = __builtin_nontemporal_load(
            reinterpret_cast<const f32x4*>(&x[xoff[i] + (t + 1) * H_DIM]));
    }
    __syncthreads();                  // all waves' H/Xs[cur] reads done
    // epilogue: GRU cell. C/D layout: col=mr, row=quad*4+reg.
#pragma unroll
    for (int im = 0; im < 2; ++im)
#pragma unroll
      for (int cf = 0; cf < 2; ++cf)
#pragma unroll
        for (int r = 0; r < 4; ++r) {
          int m = im * 16 + quad * 4 + r;
          int idx = m * LSTR + cf * 16 + mr;   // chunk = wid (j>>5), kk = j&31
          float rg = 1.0f / (1.0f + expf(-(accR[im][cf][r] + br_[cf])));
          float zg = 1.0f / (1.0f + expf(-(accZ[im][cf][r] + bz_[cf])));
          float ng = tanhf(accXN[im][cf][r] + bxn_[cf] + rg * (accHN[im][cf][r] + bhn_[cf]));
          float hp = (float)Hh[wid][idx] + (float)Hl[wid][idx];
          float hv = (1.0f - zg) * ng + zg * hp;
          f16 hi = (f16)hv;
          Hh[wid][idx] = hi;
          Hl[wid][idx] = (f16)(hv - (float)hi);
          if (t == sLen[m] - 1)
            last[(size_t)sOrd[m] * H_DIM + (jw + cf * 16 + mr)] = hv;
        }
    if (t + 1 < maxl) {
      // commit x(t+1) -> Xs[cur^1]; covered by the closing barrier.
#pragma unroll
      for (int i = 0; i < 4; ++i) {
        f16x4 hx;
        hx[0] = (f16)xr[i][0]; hx[1] = (f16)xr[i][1];
        hx[2] = (f16)xr[i][2]; hx[3] = (f16)xr[i][3];
        *reinterpret_cast<f16x4*>(
            &Xs[cur ^ 1][xc44[i] >> 5][xrow4[i] * LSTR + (xc44[i] & 31)]) = hx;
      }
    }
    __syncthreads();                  // H writes + Xs[cur^1] visible
  }
}

// ------------------------------------------------------------------
// 128x128 f16 MFMA GEMM, B always pre-split f16 [N,K] (B0=hi, B1=lo).
// AMODE 0: A f32 [M,K], on-the-fly hi/lo split.
// AMODE 1: A = bitmask (u32 words, K/32 per row) -> 0/1 f16.
// AMODE 2: A pre-split f16 [M,K] hi/lo (Ahi/Alo).
// NTERMS: 1 = Ah*Bh; 2 = +Al*Bh; 3 = +Ah*Bl.
// EPI: 0 store C f32; 1 threshold->bitmask (ballot); 2 store C*scale_m[m];
//      3 atomicAdd C += v*scale_m[m].
// SYMM (EPI=1): grid is triangular (skip by>bx); off-diag blocks also write
// the transposed bitmask chunk via ballot-transpose.
template<int AMODE, int NTERMS, int EPI, int SYMM>
__global__ __launch_bounds__(256)
void k_gemm(const float* __restrict__ A, const f16* __restrict__ Ahi,
            const f16* __restrict__ Alo, const u32* __restrict__ Abits,
            const f16* __restrict__ B0, const f16* __restrict__ B1,
            float* __restrict__ C, u16* __restrict__ bitsOut,
            const float* __restrict__ scale_m, const float* __restrict__ phi_p,
            int M, int Nn, int K, int kLen) {
  int bx = blockIdx.x, by = blockIdx.y;
  if (SYMM && by > bx) return;
  int n0 = bx * 128, m0 = by * 128;
  int kStart = blockIdx.z * kLen;
  constexpr int SB = 128 * LSTR;
  constexpr int NBUF = (NTERMS == 3) ? 4 : ((NTERMS == 2) ? 3 : 2);
  __shared__ f16 smem[SB * NBUF];
  f16* Ah = smem;
  f16* Bh = smem + SB;
  f16* Al = smem + 2 * SB;   // valid iff NTERMS>=2
  f16* Bl = smem + 3 * SB;   // valid iff NTERMS==3
  int tid = threadIdx.x;
  int lane = tid & 63, wid = tid >> 6;
  int wm = wid & 1, wn = wid >> 1;
  int quad = lane >> 4, mr = lane & 15;
  f32x4 acc[4][4] = {};
  const int nkt = kLen >> 5;
  for (int kt = 0; kt < nkt; ++kt) {
    int kg = kStart + (kt << 5);
    if (AMODE == 0) {
#pragma unroll
      for (int i = 0; i < 4; ++i) {
        int q = tid + 256 * i;          // 1024 float4: 128 rows x 8
        int row = q >> 3, kc = (q & 7) << 2;
        float4 v = *reinterpret_cast<const float4*>(&A[(size_t)(m0 + row) * K + kg + kc]);
        f16 h0_ = (f16)v.x, h1_ = (f16)v.y, h2_ = (f16)v.z, h3_ = (f16)v.w;
        f16x4 hh; hh[0] = h0_; hh[1] = h1_; hh[2] = h2_; hh[3] = h3_;
        *reinterpret_cast<f16x4*>(&Ah[row * LSTR + kc]) = hh;
        if (NTERMS >= 2) {
          f16x4 hl;
          hl[0] = (f16)(v.x - (float)h0_); hl[1] = (f16)(v.y - (float)h1_);
          hl[2] = (f16)(v.z - (float)h2_); hl[3] = (f16)(v.w - (float)h3_);
          *reinterpret_cast<f16x4*>(&Al[row * LSTR + kc]) = hl;
        }
      }
    } else if (AMODE == 2) {
#pragma unroll
      for (int i = 0; i < 2; ++i) {
        int c = tid + 256 * i;          // 512 chunks of 8 f16
        int row = c >> 2, kc = (c & 3) << 3;
        f16x8 v = *reinterpret_cast<const f16x8*>(&Ahi[(size_t)(m0 + row) * K + kg + kc]);
        st8lds(&Ah[row * LSTR + kc], v);
        if (NTERMS >= 2) {
          f16x8 v2 = *reinterpret_cast<const f16x8*>(&Alo[(size_t)(m0 + row) * K + kg + kc]);
          st8lds(&Al[row * LSTR + kc], v2);
        }
      }
    } else {
      if (tid < 128) {
        int row = tid;
        u32 w = Abits[(size_t)(m0 + row) * (K >> 5) + (kg >> 5)];
        u32* dst = reinterpret_cast<u32*>(&Ah[row * LSTR]);
#pragma unroll
        for (int p = 0; p < 16; ++p) {
          union { f16 h[2]; u32 u; } pk;
          pk.h[0] = ((w >> (2 * p)) & 1u) ? (f16)1.0f : (f16)0.0f;
          pk.h[1] = ((w >> (2 * p + 1)) & 1u) ? (f16)1.0f : (f16)0.0f;
          dst[p] = pk.u;
        }
      }
    }
    // B stage: pre-split f16 [N,K]
#pragma unroll
    for (int i = 0; i < 2; ++i) {
      int c = tid + 256 * i;            // 512 chunks of 8 f16
      int row = c >> 2, kc = (c & 3) << 3;
      f16x8 v = *reinterpret_cast<const f16x8*>(&B0[(size_t)(n0 + row) * K + kg + kc]);
      st8lds(&Bh[row * LSTR + kc], v);
      if (NTERMS == 3) {
        f16x8 v2 = *reinterpret_cast<const f16x8*>(&B1[(size_t)(n0 + row) * K + kg + kc]);
        st8lds(&Bl[row * LSTR + kc], v2);
      }
    }
    __syncthreads();
    f16x8 af[4], bf[4], alr[4], blr[4];
#pragma unroll
    for (int im = 0; im < 4; ++im) {
      af[im] = ld8lds(&Ah[(wm * 64 + im * 16 + mr) * LSTR + quad * 8]);
      if (NTERMS >= 2)
        alr[im] = ld8lds(&Al[(wm * 64 + im * 16 + mr) * LSTR + quad * 8]);
    }
#pragma unroll
    for (int in = 0; in < 4; ++in) {
      bf[in] = ld8lds(&Bh[(wn * 64 + in * 16 + mr) * LSTR + quad * 8]);
      if (NTERMS == 3)
        blr[in] = ld8lds(&Bl[(wn * 64 + in * 16 + mr) * LSTR + quad * 8]);
    }
#pragma unroll
    for (int im = 0; im < 4; ++im)
#pragma unroll
      for (int in = 0; in < 4; ++in) {
        acc[im][in] = __builtin_amdgcn_mfma_f32_16x16x32_f16(af[im], bf[in], acc[im][in], 0, 0, 0);
        if (NTERMS >= 2)
          acc[im][in] = __builtin_amdgcn_mfma_f32_16x16x32_f16(alr[im], bf[in], acc[im][in], 0, 0, 0);
        if (NTERMS == 3)
          acc[im][in] = __builtin_amdgcn_mfma_f32_16x16x32_f16(af[im], blr[in], acc[im][in], 0, 0, 0);
      }
    __syncthreads();
  }
  float phiK = 0.0f;
  if (EPI == 1) phiK = phi_p[0] * 65536.0f;   // dot/65536 >= phi  <=>  dot >= phi*65536 (exact, pow2)
#pragma unroll
  for (int im = 0; im < 4; ++im) {
#pragma unroll
    for (int in = 0; in < 4; ++in) {
      int nn = n0 + wn * 64 + in * 16 + mr;
      int mb = m0 + wm * 64 + im * 16 + quad * 4;
      if (EPI == 1) {
        u64 bal[4];
#pragma unroll
        for (int r = 0; r < 4; ++r) {
          int m = mb + r;
          bool one = (acc[im][in][r] >= phiK) || (m == nn);   // diag forced to 1
          bal[r] = __ballot(one);
        }
#pragma unroll
        for (int r = 0; r < 4; ++r) {
          if (mr == 0) {
            u16 chunk = (u16)((bal[r] >> (16 * quad)) & 0xFFFFu);
            bitsOut[(size_t)(mb + r) * (Nn >> 4) + (nn >> 4)] = chunk;
          }
        }
        if (SYMM && m0 != n0) {
          // transposed chunk: row nn (by mr), 16 m-bits j=quad'*4+r'
          u32 tb = 0;
#pragma unroll
          for (int jb = 0; jb < 16; ++jb)
            tb |= (u32)((bal[jb & 3] >> ((jb >> 2) * 16 + mr)) & 1ull) << jb;
          if (quad == 0) {
            int nnr = n0 + wn * 64 + in * 16 + mr;
            int mch = (m0 + wm * 64 + im * 16) >> 4;
            bitsOut[(size_t)nnr * (Nn >> 4) + mch] = (u16)tb;
          }
        }
      } else {
#pragma unroll
        for (int r = 0; r < 4; ++r) {
          int m = mb + r;
          float v = acc[im][in][r];
          if (EPI == 0) {
            C[(size_t)m * Nn + nn] = v;
          } else if (EPI == 2) {
            C[(size_t)m * Nn + nn] = v * scale_m[m];
          } else {
            atomicAdd(&C[(size_t)m * Nn + nn], v * scale_m[m]);
          }
        }
      }
    }
  }
}

// ------------------------------------------------------------------
__global__ void k_split16(const float* __restrict__ src, f16* __restrict__ hi,
                          f16* __restrict__ lo) {
  int i = blockIdx.x * 256 + threadIdx.x;   // N*H
  float v = src[i];
  f16 h = (f16)v;
  hi[i] = h; lo[i] = (f16)(v - (float)h);
}

__global__ void k_degdis(const u32* __restrict__ bits, float* __restrict__ dis) {
  __shared__ int red[4];
  int row = blockIdx.x, tid = threadIdx.x;
  u32 w = bits[(size_t)row * 256 + tid];
  int c = __popc(w);
  for (int off = 32; off > 0; off >>= 1) c += __shfl_down(c, off);
  if ((tid & 63) == 0) red[tid >> 6] = c;
  __syncthreads();
  if (tid == 0) {
    int s = red[0] + red[1] + red[2] + red[3];
    dis[row] = s > 0 ? rsqrtf((float)s) : 0.0f;
  }
}

__global__ void k_outinit(const float* __restrict__ b, float* __restrict__ out) {
  int i = blockIdx.x * 256 + threadIdx.x;
  out[i] = b[i & (H_DIM - 1)];
}

// ------------------------------------------------------------------
extern "C" void kernel_launch(void* const* d_in, const int* in_sizes, int n_in,
                              void* d_out, int out_size, void* d_ws, size_t ws_size,
                              hipStream_t stream) {
  (void)in_sizes; (void)n_in; (void)out_size; (void)ws_size;
  const float* x    = (const float*)d_in[0];
  const int*   he   = (const int*)d_in[1];
  const int*   slen = (const int*)d_in[2];
  const float* h0   = (const float*)d_in[3];
  const float* wih  = (const float*)d_in[4];
  const float* whh  = (const float*)d_in[5];
  const float* bih  = (const float*)d_in[6];
  const float* bhh  = (const float*)d_in[7];
  const float* hw[3] = {(const float*)d_in[8], (const float*)d_in[10], (const float*)d_in[12]};
  const float* hb[3] = {(const float*)d_in[9], (const float*)d_in[11], (const float*)d_in[13]};
  const float* phi  = (const float*)d_in[14];
  const float* gw   = (const float*)d_in[15];
  const float* gb   = (const float*)d_in[16];
  float* out = (float*)d_out;

  // ---- workspace layout, everything re-initialized every call ----
  size_t off = 0;
  char* wsb = (char*)d_ws;
  auto alloc = [&](size_t b) { void* p = wsb + off; off += (b + 255) & ~(size_t)255; return p; };
  int*   order = (int*)alloc(N_NODES * 4);
  int*   lens  = (int*)alloc(N_NODES * 4);
  int*   Mts   = (int*)alloc(256);
  u32*   histD = (u32*)alloc(N_NODES * 4);
  u32*   histB = (u32*)alloc(N_EDGES * 4);
  float* dinv  = (float*)alloc(N_NODES * 4);
  float* binv  = (float*)alloc(N_EDGES * 4);
  float* dis   = (float*)alloc(N_NODES * 4);
  int*   noff  = (int*)alloc((N_NODES + 1) * 4);
  int*   eoff  = (int*)alloc((N_EDGES + 1) * 4);
  int*   ncur  = (int*)alloc(N_NODES * 4);
  int*   ecur  = (int*)alloc(N_EDGES * 4);
  int*   nlist = (int*)alloc(NNZ_ * 4);
  int*   elist = (int*)alloc(NNZ_ * 4);
  f16*   wihp  = (f16*)alloc(768 * 256 * 2);   // packed fragment-order weights
  f16*   whhp  = (f16*)alloc(768 * 256 * 2);
  f16*   hwT[3]; f16* hwTlo[3];
  for (int c = 0; c < 3; ++c) {
    hwT[c]   = (f16*)alloc(256 * 256 * 2);
    hwTlo[c] = (f16*)alloc(256 * 256 * 2);
  }
  f16*   gwT   = (f16*)alloc(256 * 256 * 2);
  f16*   gwTlo = (f16*)alloc(256 * 256 * 2);
  float* oA    = (float*)alloc((size_t)N_NODES * H_DIM * 4);   // `last`, then o2
  float* oB    = (float*)alloc((size_t)N_NODES * H_DIM * 4);   // o1, then o3
  float* xwb   = (float*)alloc((size_t)N_NODES * H_DIM * 4);   // xw scratch / z
  float* eb    = (float*)alloc((size_t)N_EDGES * H_DIM * 4);
  f16*   o3hi  = (f16*)alloc((size_t)N_NODES * H_DIM * 2);
  f16*   o3lo  = (f16*)alloc((size_t)N_NODES * H_DIM * 2);
  f16*   z16T  = (f16*)alloc((size_t)H_DIM * N_NODES * 2);     // z^T [256][8192]
  u32*   Abits = (u32*)alloc((size_t)N_NODES * 256 * 4);       // 8192x8192 bits

  // ---- preprocessing ----
  k_sort<<<1, 256, 0, stream>>>(slen, order, lens, Mts);
  k_wpack<<<768, 256, 0, stream>>>(wih, whh, wihp, whhp);
  hipMemsetAsync(histD, 0, N_NODES * 4, stream);
  hipMemsetAsync(histB, 0, N_EDGES * 4, stream);
  k_hist<<<NNZ_ / 256, 256, 0, stream>>>(he, histD, histB);
  k_inv<<<N_NODES / 256, 256, 0, stream>>>(histD, histB, dinv, binv);
  k_scan<<<1, 256, 0, stream>>>(histD, histB, noff, eoff, ncur, ecur);
  k_fill<<<NNZ_ / 256, 256, 0, stream>>>(he, ncur, ecur, nlist, elist);
  for (int c = 0; c < 3; ++c)
    k_tsplit<<<dim3(4, 4), 256, 0, stream>>>(hw[c], hwT[c], hwTlo[c], 256, 256, 1);
  k_tsplit<<<dim3(4, 4), 256, 0, stream>>>(gw, gwT, gwTlo, 256, 256, 1);

  // ---- GRU: ONE persistent launch, all 32 steps, h resident in LDS ----
  k_gru_all<<<N_NODES / 32, 512, 0, stream>>>(x, h0, oA, wihp, whhp,
                                              bih, bhh, order, lens);
  // oA now holds `last` in original node order.

  // ---- 3x HypergraphConv with residual (CSR gather, no atomics) ----
  float* prev = oA; float* nxt = oB;
  for (int c = 0; c < 3; ++c) {
    k_gemm<0, 3, 0, 0><<<dim3(2, 64, 1), 256, 0, stream>>>(
        prev, nullptr, nullptr, nullptr, hwT[c], hwTlo[c], xwb, nullptr,
        nullptr, nullptr, N_NODES, H_DIM, H_DIM, H_DIM);
    k_edge_gather<<<N_EDGES, 256, 0, stream>>>(xwb, eoff, nlist, binv, eb);
    k_node_gather<<<N_NODES, 256, 0, stream>>>(eb, noff, elist, dinv, prev, hb[c], nxt);
    float* tmp = prev; prev = nxt; nxt = tmp;
  }
  float* o3 = prev;  // == oB after 3 swaps

  // ---- dynamic adjacency: gram -> bitmask (triangular + mirrored), degrees ----
  k_split16<<<N_NODES, 256, 0, stream>>>(o3, o3hi, o3lo);
  k_gemm<2, 3, 1, 1><<<dim3(64, 64, 1), 256, 0, stream>>>(
      nullptr, o3hi, o3lo, nullptr, o3hi, o3lo, nullptr, (u16*)Abits,
      nullptr, phi, N_NODES, N_NODES, H_DIM, H_DIM);
  k_degdis<<<N_NODES, 256, 0, stream>>>(Abits, dis);

  // ---- z = dis .* (o3 @ gcn_w), then transpose-split to z16T ----
  k_gemm<2, 3, 2, 0><<<dim3(2, 64, 1), 256, 0, stream>>>(
      nullptr, o3hi, o3lo, nullptr, gwT, gwTlo, xwb, nullptr,
      dis, nullptr, N_NODES, H_DIM, H_DIM, H_DIM);
  k_tsplit<<<dim3(128, 4), 256, 0, stream>>>(xwb, z16T, nullptr, N_NODES, H_DIM, 0);

  // ---- out = dis .* (A @ z) + gcn_b  (bitmask A in LDS, split-K=4) ----
  k_outinit<<<N_NODES, 256, 0, stream>>>(gb, out);
  k_gemm<1, 1, 3, 0><<<dim3(2, 64, 4), 256, 0, stream>>>(
      nullptr, nullptr, nullptr, Abits, z16T, nullptr, out, nullptr,
      dis, nullptr, N_NODES, H_DIM, N_NODES, N_NODES / 4);
}

// Round 7
// 1196.991 us; speedup vs baseline: 1.4460x; 1.0940x over previous
//
#include <hip/hip_runtime.h>
#include <cstdint>
#include <cstddef>

typedef _Float16 f16;
typedef __attribute__((ext_vector_type(4))) _Float16 f16x4;
typedef __attribute__((ext_vector_type(8))) _Float16 f16x8;
typedef __attribute__((ext_vector_type(4))) float f32x4;
typedef uint32_t u32;
typedef uint16_t u16;
typedef unsigned long long u64;

#define N_NODES 8192
#define T_STEPS 32
#define H_DIM   256
#define N_EDGES 1024
#define NNZ_    65536

// LDS row stride: 36 f16 = 18 words; mr*18 mod 32 has 16 distinct residues
// -> conflict-free fragment reads (vs 40 f16 = 20 words, period 8, 2-4x conflicts).
#define LSTR 36

__device__ __forceinline__ f16x8 ld8lds(const f16* p) {
  union { f16x8 v8; f16x4 v4[2]; } u;
  u.v4[0] = *reinterpret_cast<const f16x4*>(p);
  u.v4[1] = *reinterpret_cast<const f16x4*>(p + 4);
  return u.v8;
}
__device__ __forceinline__ void st8lds(f16* p, f16x8 v) {
  union { f16x8 v8; f16x4 v4[2]; } u; u.v8 = v;
  *reinterpret_cast<f16x4*>(p) = u.v4[0];
  *reinterpret_cast<f16x4*>(p + 4) = u.v4[1];
}

// ------------------------------------------------------------------
// counting sort of nodes by length, descending. Also emits M_t = #{len>t}.
__global__ void k_sort(const int* __restrict__ len, int* __restrict__ order,
                       int* __restrict__ len_s, int* __restrict__ Mts) {
  __shared__ int hist[33];
  __shared__ int cur[33];
  int tid = threadIdx.x;
  if (tid < 33) hist[tid] = 0;
  __syncthreads();
  for (int i = tid; i < N_NODES; i += 256) {
    int l = len[i]; l = l < 0 ? 0 : (l > 32 ? 32 : l);
    atomicAdd(&hist[l], 1);
  }
  __syncthreads();
  if (tid == 0) {
    int acc = 0;
    for (int l = 32; l >= 0; --l) { cur[l] = acc; acc += hist[l]; }
    for (int t = 0; t < 32; ++t) Mts[t] = cur[t];  // cur[t] = #{len > t}
  }
  __syncthreads();
  for (int i = tid; i < N_NODES; i += 256) {
    int l = len[i]; l = l < 0 ? 0 : (l > 32 ? 32 : l);
    int pos = atomicAdd(&cur[l], 1);
    order[pos] = i; len_s[pos] = l;
  }
}

// Pack GRU weights into MFMA-fragment order so fragment loads are fully
// coalesced (lane-contiguous). Packed layout, per matrix (wih / whh):
//   tile = (kt*16 + jt)*3 + g          (384 tiles of 512 f16 = 1 KB)
//   within-tile offset = (quad*16 + mr)*8 + e  = lane*8 + e
//   source element = W[g*256 + jt*16 + mr][kt*32 + quad*8 + e]
// A wave's fragment load (fixed kt, jt, g) is then base + lane*16B ->
// one contiguous 1 KB read (8 fully-used 128B lines) instead of 64
// partially-used lines (the round-4 L2-amplification bottleneck).
__global__ void k_wpack(const float* __restrict__ wih, const float* __restrict__ whh,
                        f16* __restrict__ wihp, f16* __restrict__ whhp) {
  int i = blockIdx.x * 256 + threadIdx.x;        // 768*256 = 196608 elems
  int tile = i >> 9, within = i & 511;
  int quad = within >> 7, mr = (within >> 3) & 15, e = within & 7;
  int g = tile % 3, t3 = tile / 3;
  int jt = t3 & 15, kt = t3 >> 4;
  int row = g * 256 + jt * 16 + mr;
  int col = kt * 32 + quad * 8 + e;
  wihp[i] = (f16)wih[row * 256 + col];
  whhp[i] = (f16)whh[row * 256 + col];
}

__global__ void k_hist(const int* __restrict__ he, u32* __restrict__ hd, u32* __restrict__ hb) {
  int i = blockIdx.x * 256 + threadIdx.x;
  if (i < NNZ_) {
    atomicAdd(&hd[he[i]], 1u);
    atomicAdd(&hb[he[NNZ_ + i]], 1u);
  }
}

__global__ void k_inv(const u32* __restrict__ hd, const u32* __restrict__ hb,
                      float* __restrict__ dinv, float* __restrict__ binv) {
  int i = blockIdx.x * 256 + threadIdx.x;
  if (i < N_NODES) dinv[i] = hd[i] ? 1.0f / (float)hd[i] : 0.0f;
  if (i < N_EDGES) binv[i] = hb[i] ? 1.0f / (float)hb[i] : 0.0f;
}

// ------------------------------------------------------------------
// Exclusive prefix scan of node/edge histograms -> CSR offsets + cursors.
__global__ void k_scan(const u32* __restrict__ histD, const u32* __restrict__ histB,
                       int* __restrict__ noff, int* __restrict__ eoff,
                       int* __restrict__ ncur, int* __restrict__ ecur) {
  __shared__ int buf[256];
  __shared__ int base;
  int tid = threadIdx.x;
  if (tid == 0) base = 0;
  __syncthreads();
  for (int ch = 0; ch < N_NODES / 256; ++ch) {
    int i = ch * 256 + tid;
    int v = (int)histD[i];
    buf[tid] = v; __syncthreads();
    for (int off = 1; off < 256; off <<= 1) {
      int t = (tid >= off) ? buf[tid - off] : 0; __syncthreads();
      buf[tid] += t; __syncthreads();
    }
    int excl = base + buf[tid] - v;
    noff[i] = excl; ncur[i] = excl;
    __syncthreads();
    if (tid == 255) { base += buf[255]; if (i == N_NODES - 1) noff[N_NODES] = base; }
    __syncthreads();
  }
  if (tid == 0) base = 0;
  __syncthreads();
  for (int ch = 0; ch < N_EDGES / 256; ++ch) {
    int i = ch * 256 + tid;
    int v = (int)histB[i];
    buf[tid] = v; __syncthreads();
    for (int off = 1; off < 256; off <<= 1) {
      int t = (tid >= off) ? buf[tid - off] : 0; __syncthreads();
      buf[tid] += t; __syncthreads();
    }
    int excl = base + buf[tid] - v;
    eoff[i] = excl; ecur[i] = excl;
    __syncthreads();
    if (tid == 255) { base += buf[255]; if (i == N_EDGES - 1) eoff[N_EDGES] = base; }
    __syncthreads();
  }
}

__global__ void k_fill(const int* __restrict__ he, int* __restrict__ ncur,
                       int* __restrict__ ecur, int* __restrict__ nlist,
                       int* __restrict__ elist) {
  int i = blockIdx.x * 256 + threadIdx.x;
  if (i < NNZ_) {
    int node = he[i], edge = he[NNZ_ + i];
    int p1 = atomicAdd(&ecur[edge], 1); nlist[p1] = node;  // per-edge node list
    int p2 = atomicAdd(&ncur[node], 1); elist[p2] = edge;  // per-node edge list
  }
}

// e[edge][c] = Binv[edge] * sum_{node in edge} xw[node][c]   (gather, no atomics)
__global__ __launch_bounds__(256)
void k_edge_gather(const float* __restrict__ xw, const int* __restrict__ eoff,
                   const int* __restrict__ nlist, const float* __restrict__ binv,
                   float* __restrict__ e) {
  int edge = blockIdx.x, c = threadIdx.x;
  int s = eoff[edge], t = eoff[edge + 1];
  __shared__ int nds[256];
  float sum = 0.0f;
  for (int base = s; base < t; base += 256) {
    int nchunk = t - base; if (nchunk > 256) nchunk = 256;
    if (c < nchunk) nds[c] = nlist[base + c];
    __syncthreads();
    for (int k = 0; k < nchunk; ++k)
      sum += xw[(size_t)nds[k] * H_DIM + c];
    __syncthreads();
  }
  e[(size_t)edge * H_DIM + c] = sum * binv[edge];
}

// out[node][c] = prev[node][c] + bias[c] + Dinv[node] * sum_{edge in node} e[edge][c]
__global__ __launch_bounds__(256)
void k_node_gather(const float* __restrict__ e, const int* __restrict__ noff,
                   const int* __restrict__ elist, const float* __restrict__ dinv,
                   const float* __restrict__ prev, const float* __restrict__ bias,
                   float* __restrict__ outp) {
  int node = blockIdx.x, c = threadIdx.x;
  int s = noff[node], t = noff[node + 1];
  __shared__ int eds[64];
  float sum = 0.0f;
  for (int base = s; base < t; base += 64) {
    int nchunk = t - base; if (nchunk > 64) nchunk = 64;
    if (c < nchunk) eds[c] = elist[base + c];
    __syncthreads();
    for (int k = 0; k < nchunk; ++k)
      sum += e[(size_t)eds[k] * H_DIM + c];
    __syncthreads();
  }
  outp[(size_t)node * H_DIM + c] =
      prev[(size_t)node * H_DIM + c] + bias[c] + dinv[node] * sum;
}

// ------------------------------------------------------------------
// Transpose + f16 hi/lo split: src [Mp][Np] f32 -> hiT/loT [Np][Mp] f16.
__global__ __launch_bounds__(256)
void k_tsplit(const float* __restrict__ src, f16* __restrict__ hiT,
              f16* __restrict__ loT, int Mp, int Np, int withLo) {
  __shared__ float tile[64][65];
  int m0 = blockIdx.x * 64, n0 = blockIdx.y * 64;
  int tid = threadIdx.x;
#pragma unroll
  for (int i = 0; i < 4; ++i) {
    int q = tid + 256 * i;             // 1024 float4 = 64 rows x 64 cols
    int row = q >> 4, c4 = (q & 15) << 2;
    float4 v = *reinterpret_cast<const float4*>(&src[(size_t)(m0 + row) * Np + n0 + c4]);
    tile[row][c4] = v.x; tile[row][c4 + 1] = v.y;
    tile[row][c4 + 2] = v.z; tile[row][c4 + 3] = v.w;
  }
  __syncthreads();
#pragma unroll
  for (int i = 0; i < 4; ++i) {
    int q = tid + 256 * i;
    int nrow = q >> 4, mc = (q & 15) << 2;
    f16x4 h, l;
#pragma unroll
    for (int j = 0; j < 4; ++j) {
      float v = tile[mc + j][nrow];
      h[j] = (f16)v;
      l[j] = (f16)(v - (float)h[j]);
    }
    *reinterpret_cast<f16x4*>(&hiT[(size_t)(n0 + nrow) * Mp + m0 + mc]) = h;
    if (withLo)
      *reinterpret_cast<f16x4*>(&loT[(size_t)(n0 + nrow) * Mp + m0 + mc]) = l;
  }
}

// ------------------------------------------------------------------
// Persistent GRU: ONE launch for all 32 time steps.
// Round-7: round-6 structure with the launch-bounds spill fixed.
//  - Round-6's __launch_bounds__(512,4) capped unified VGPR+AGPR at 128;
//    live set is ~190 (64 acc + 48 weight frags + 16 x-prefetch + misc) ->
//    weight frags spilled to scratch (VGPR_Count 64, WRITE 136 MB). And the
//    cap bought nothing: 256 blocks on 256 CUs = 1 block/CU always, so
//    occupancy is 2 waves/SIMD regardless. (512,2) gives the 256-reg
//    budget; round-4 proved this config spill-free.
//  - Geometry: 256 blocks x 32 rows x 512 thr; packed fragment-order
//    weights (lane-contiguous 1 KB wave-loads); Xs double-buffered,
//    2 barriers/step; runtime kt loop, single-buffered 12-frag weights.
//  - Expected regime: L2 weight stream (768 KB/block/step, 24.6 MB/XCD/step
//    at ~4.3 TB/s per-XCD) ~ 5.7 us/step floor; MFMA ~1.2 us under it.
__global__ __launch_bounds__(512, 2)
void k_gru_all(const float* __restrict__ x, const float* __restrict__ h0,
               float* __restrict__ last,
               const f16* __restrict__ wihp, const f16* __restrict__ whhp,
               const float* __restrict__ bih, const float* __restrict__ bhh,
               const int* __restrict__ order, const int* __restrict__ len_s) {
  __shared__ f16 Xs[2][8][32 * LSTR];  // x tile, double-buffered (cur = t&1)
  __shared__ f16 Hh[8][32 * LSTR];     // h hi
  __shared__ f16 Hl[8][32 * LSTR];     // h lo
  __shared__ int sOrd[32], sLen[32];
  int tid = threadIdx.x;
  int r0 = blockIdx.x * 32;
  if (tid < 32) { sOrd[tid] = order[r0 + tid]; sLen[tid] = len_s[r0 + tid]; }
  for (int i = tid; i < 32 * 256; i += 512) {
    int row = i >> 8, k = i & 255;
    float v = h0[k];
    f16 hi = (f16)v;
    int idx = row * LSTR + (k & 31);
    Hh[k >> 5][idx] = hi;
    Hl[k >> 5][idx] = (f16)(v - (float)hi);
  }
  __syncthreads();                    // sOrd ready (for xoff below)
  int maxl = sLen[0];                 // sorted desc -> first row of stripe is max
  int lane = tid & 63, wid = tid >> 6;
  int quad = lane >> 4, mr = lane & 15;
  int jw = wid * 32;                  // this wave's 32 h-columns
  float br_[2], bz_[2], bxn_[2], bhn_[2];
  int wboff[2][3];                    // packed-layout fragment offsets
#pragma unroll
  for (int cf = 0; cf < 2; ++cf) {
    int j = jw + cf * 16 + mr;
    br_[cf]  = bih[j] + bhh[j];
    bz_[cf]  = bih[256 + j] + bhh[256 + j];
    bxn_[cf] = bih[512 + j];
    bhn_[cf] = bhh[512 + j];
    int jt = wid * 2 + cf;
#pragma unroll
    for (int g = 0; g < 3; ++g)
      wboff[cf][g] = (jt * 3 + g) * 512 + lane * 8;
  }
  // per-thread x element offsets (4 float4 = 32 rows x 64 col-groups / 512 thr)
  int xoff[4], xrow4[4], xc44[4];
#pragma unroll
  for (int i = 0; i < 4; ++i) {
    int q = tid + 512 * i;
    xrow4[i] = q >> 6; xc44[i] = (q & 63) << 2;
    xoff[i] = sOrd[xrow4[i]] * (T_STEPS * H_DIM) + xc44[i];
  }
  f32x4 xr[4];
#pragma unroll
  for (int i = 0; i < 4; ++i)         // load t=0 (nontemporal, evict-first)
    xr[i] = __builtin_nontemporal_load(reinterpret_cast<const f32x4*>(&x[xoff[i]]));
  // commit x(0) -> Xs[0]
#pragma unroll
  for (int i = 0; i < 4; ++i) {
    f16x4 hx;
    hx[0] = (f16)xr[i][0]; hx[1] = (f16)xr[i][1];
    hx[2] = (f16)xr[i][2]; hx[3] = (f16)xr[i][3];
    *reinterpret_cast<f16x4*>(&Xs[0][xc44[i] >> 5][xrow4[i] * LSTR + (xc44[i] & 31)]) = hx;
  }
  __syncthreads();                    // H init + Xs[0] visible

  for (int t = 0; t < maxl; ++t) {
    int cur = t & 1;
    f32x4 accR[2][2] = {}, accZ[2][2] = {}, accXN[2][2] = {}, accHN[2][2] = {};
    // RUNTIME k-chunk loop: unroll disabled so only ONE iteration's weight
    // loads are in flight -> no register-pressure blowup, no scratch spills.
#pragma clang loop unroll(disable)
    for (int kt = 0; kt < 8; ++kt) {
      const f16* pih = wihp + kt * 24576;   // 16 jt * 3 g * 512
      const f16* phh = whhp + kt * 24576;
      f16x8 bf[12];                   // single-buffered weight frags (48 VGPR)
#pragma unroll
      for (int cf = 0; cf < 2; ++cf)
#pragma unroll
        for (int g = 0; g < 3; ++g) {
          bf[cf * 6 + g * 2 + 0] = *reinterpret_cast<const f16x8*>(&pih[wboff[cf][g]]);
          bf[cf * 6 + g * 2 + 1] = *reinterpret_cast<const f16x8*>(&phh[wboff[cf][g]]);
        }
#pragma unroll
      for (int im = 0; im < 2; ++im) {
        f16x8 ax = ld8lds(&Xs[cur][kt][(im * 16 + mr) * LSTR + quad * 8]);
        f16x8 ah = ld8lds(&Hh[kt][(im * 16 + mr) * LSTR + quad * 8]);
        f16x8 al = ld8lds(&Hl[kt][(im * 16 + mr) * LSTR + quad * 8]);
#pragma unroll
        for (int cf = 0; cf < 2; ++cf) {
          accR[im][cf]  = __builtin_amdgcn_mfma_f32_16x16x32_f16(ax, bf[cf*6+0], accR[im][cf], 0, 0, 0);
          accR[im][cf]  = __builtin_amdgcn_mfma_f32_16x16x32_f16(ah, bf[cf*6+1], accR[im][cf], 0, 0, 0);
          accR[im][cf]  = __builtin_amdgcn_mfma_f32_16x16x32_f16(al, bf[cf*6+1], accR[im][cf], 0, 0, 0);
          accZ[im][cf]  = __builtin_amdgcn_mfma_f32_16x16x32_f16(ax, bf[cf*6+2], accZ[im][cf], 0, 0, 0);
          accZ[im][cf]  = __builtin_amdgcn_mfma_f32_16x16x32_f16(ah, bf[cf*6+3], accZ[im][cf], 0, 0, 0);
          accZ[im][cf]  = __builtin_amdgcn_mfma_f32_16x16x32_f16(al, bf[cf*6+3], accZ[im][cf], 0, 0, 0);
          accXN[im][cf] = __builtin_amdgcn_mfma_f32_16x16x32_f16(ax, bf[cf*6+4], accXN[im][cf], 0, 0, 0);
          accHN[im][cf] = __builtin_amdgcn_mfma_f32_16x16x32_f16(ah, bf[cf*6+5], accHN[im][cf], 0, 0, 0);
          accHN[im][cf] = __builtin_amdgcn_mfma_f32_16x16x32_f16(al, bf[cf*6+5], accHN[im][cf], 0, 0, 0);
        }
      }
    }
    if (t + 1 < maxl) {
      // issue x(t+1) loads now; committed at END of epilogue (~2000+ cyc
      // later) so HBM latency is fully hidden.
#pragma unroll
      for (int i = 0; i < 4; ++i)
        xr[i] = __builtin_nontemporal_load(
            reinterpret_cast<const f32x4*>(&x[xoff[i] + (t + 1) * H_DIM]));
    }
    __syncthreads();                  // all waves' H/Xs[cur] reads done
    // epilogue: GRU cell. C/D layout: col=mr, row=quad*4+reg.
#pragma unroll
    for (int im = 0; im < 2; ++im)
#pragma unroll
      for (int cf = 0; cf < 2; ++cf)
#pragma unroll
        for (int r = 0; r < 4; ++r) {
          int m = im * 16 + quad * 4 + r;
          int idx = m * LSTR + cf * 16 + mr;   // chunk = wid (j>>5), kk = j&31
          float rg = 1.0f / (1.0f + expf(-(accR[im][cf][r] + br_[cf])));
          float zg = 1.0f / (1.0f + expf(-(accZ[im][cf][r] + bz_[cf])));
          float ng = tanhf(accXN[im][cf][r] + bxn_[cf] + rg * (accHN[im][cf][r] + bhn_[cf]));
          float hp = (float)Hh[wid][idx] + (float)Hl[wid][idx];
          float hv = (1.0f - zg) * ng + zg * hp;
          f16 hi = (f16)hv;
          Hh[wid][idx] = hi;
          Hl[wid][idx] = (f16)(hv - (float)hi);
          if (t == sLen[m] - 1)
            last[(size_t)sOrd[m] * H_DIM + (jw + cf * 16 + mr)] = hv;
        }
    if (t + 1 < maxl) {
      // commit x(t+1) -> Xs[cur^1]; covered by the closing barrier.
#pragma unroll
      for (int i = 0; i < 4; ++i) {
        f16x4 hx;
        hx[0] = (f16)xr[i][0]; hx[1] = (f16)xr[i][1];
        hx[2] = (f16)xr[i][2]; hx[3] = (f16)xr[i][3];
        *reinterpret_cast<f16x4*>(
            &Xs[cur ^ 1][xc44[i] >> 5][xrow4[i] * LSTR + (xc44[i] & 31)]) = hx;
      }
    }
    __syncthreads();                  // H writes + Xs[cur^1] visible
  }
}

// ------------------------------------------------------------------
// 128x128 f16 MFMA GEMM, B always pre-split f16 [N,K] (B0=hi, B1=lo).
// AMODE 0: A f32 [M,K], on-the-fly hi/lo split.
// AMODE 1: A = bitmask (u32 words, K/32 per row) -> 0/1 f16.
// AMODE 2: A pre-split f16 [M,K] hi/lo (Ahi/Alo).
// NTERMS: 1 = Ah*Bh; 2 = +Al*Bh; 3 = +Ah*Bl.
// EPI: 0 store C f32; 1 threshold->bitmask (ballot); 2 store C*scale_m[m];
//      3 atomicAdd C += v*scale_m[m].
// SYMM (EPI=1): grid is triangular (skip by>bx); off-diag blocks also write
// the transposed bitmask chunk via ballot-transpose.
template<int AMODE, int NTERMS, int EPI, int SYMM>
__global__ __launch_bounds__(256)
void k_gemm(const float* __restrict__ A, const f16* __restrict__ Ahi,
            const f16* __restrict__ Alo, const u32* __restrict__ Abits,
            const f16* __restrict__ B0, const f16* __restrict__ B1,
            float* __restrict__ C, u16* __restrict__ bitsOut,
            const float* __restrict__ scale_m, const float* __restrict__ phi_p,
            int M, int Nn, int K, int kLen) {
  int bx = blockIdx.x, by = blockIdx.y;
  if (SYMM && by > bx) return;
  int n0 = bx * 128, m0 = by * 128;
  int kStart = blockIdx.z * kLen;
  constexpr int SB = 128 * LSTR;
  constexpr int NBUF = (NTERMS == 3) ? 4 : ((NTERMS == 2) ? 3 : 2);
  __shared__ f16 smem[SB * NBUF];
  f16* Ah = smem;
  f16* Bh = smem + SB;
  f16* Al = smem + 2 * SB;   // valid iff NTERMS>=2
  f16* Bl = smem + 3 * SB;   // valid iff NTERMS==3
  int tid = threadIdx.x;
  int lane = tid & 63, wid = tid >> 6;
  int wm = wid & 1, wn = wid >> 1;
  int quad = lane >> 4, mr = lane & 15;
  f32x4 acc[4][4] = {};
  const int nkt = kLen >> 5;
  for (int kt = 0; kt < nkt; ++kt) {
    int kg = kStart + (kt << 5);
    if (AMODE == 0) {
#pragma unroll
      for (int i = 0; i < 4; ++i) {
        int q = tid + 256 * i;          // 1024 float4: 128 rows x 8
        int row = q >> 3, kc = (q & 7) << 2;
        float4 v = *reinterpret_cast<const float4*>(&A[(size_t)(m0 + row) * K + kg + kc]);
        f16 h0_ = (f16)v.x, h1_ = (f16)v.y, h2_ = (f16)v.z, h3_ = (f16)v.w;
        f16x4 hh; hh[0] = h0_; hh[1] = h1_; hh[2] = h2_; hh[3] = h3_;
        *reinterpret_cast<f16x4*>(&Ah[row * LSTR + kc]) = hh;
        if (NTERMS >= 2) {
          f16x4 hl;
          hl[0] = (f16)(v.x - (float)h0_); hl[1] = (f16)(v.y - (float)h1_);
          hl[2] = (f16)(v.z - (float)h2_); hl[3] = (f16)(v.w - (float)h3_);
          *reinterpret_cast<f16x4*>(&Al[row * LSTR + kc]) = hl;
        }
      }
    } else if (AMODE == 2) {
#pragma unroll
      for (int i = 0; i < 2; ++i) {
        int c = tid + 256 * i;          // 512 chunks of 8 f16
        int row = c >> 2, kc = (c & 3) << 3;
        f16x8 v = *reinterpret_cast<const f16x8*>(&Ahi[(size_t)(m0 + row) * K + kg + kc]);
        st8lds(&Ah[row * LSTR + kc], v);
        if (NTERMS >= 2) {
          f16x8 v2 = *reinterpret_cast<const f16x8*>(&Alo[(size_t)(m0 + row) * K + kg + kc]);
          st8lds(&Al[row * LSTR + kc], v2);
        }
      }
    } else {
      if (tid < 128) {
        int row = tid;
        u32 w = Abits[(size_t)(m0 + row) * (K >> 5) + (kg >> 5)];
        u32* dst = reinterpret_cast<u32*>(&Ah[row * LSTR]);
#pragma unroll
        for (int p = 0; p < 16; ++p) {
          union { f16 h[2]; u32 u; } pk;
          pk.h[0] = ((w >> (2 * p)) & 1u) ? (f16)1.0f : (f16)0.0f;
          pk.h[1] = ((w >> (2 * p + 1)) & 1u) ? (f16)1.0f : (f16)0.0f;
          dst[p] = pk.u;
        }
      }
    }
    // B stage: pre-split f16 [N,K]
#pragma unroll
    for (int i = 0; i < 2; ++i) {
      int c = tid + 256 * i;            // 512 chunks of 8 f16
      int row = c >> 2, kc = (c & 3) << 3;
      f16x8 v = *reinterpret_cast<const f16x8*>(&B0[(size_t)(n0 + row) * K + kg + kc]);
      st8lds(&Bh[row * LSTR + kc], v);
      if (NTERMS == 3) {
        f16x8 v2 = *reinterpret_cast<const f16x8*>(&B1[(size_t)(n0 + row) * K + kg + kc]);
        st8lds(&Bl[row * LSTR + kc], v2);
      }
    }
    __syncthreads();
    f16x8 af[4], bf[4], alr[4], blr[4];
#pragma unroll
    for (int im = 0; im < 4; ++im) {
      af[im] = ld8lds(&Ah[(wm * 64 + im * 16 + mr) * LSTR + quad * 8]);
      if (NTERMS >= 2)
        alr[im] = ld8lds(&Al[(wm * 64 + im * 16 + mr) * LSTR + quad * 8]);
    }
#pragma unroll
    for (int in = 0; in < 4; ++in) {
      bf[in] = ld8lds(&Bh[(wn * 64 + in * 16 + mr) * LSTR + quad * 8]);
      if (NTERMS == 3)
        blr[in] = ld8lds(&Bl[(wn * 64 + in * 16 + mr) * LSTR + quad * 8]);
    }
#pragma unroll
    for (int im = 0; im < 4; ++im)
#pragma unroll
      for (int in = 0; in < 4; ++in) {
        acc[im][in] = __builtin_amdgcn_mfma_f32_16x16x32_f16(af[im], bf[in], acc[im][in], 0, 0, 0);
        if (NTERMS >= 2)
          acc[im][in] = __builtin_amdgcn_mfma_f32_16x16x32_f16(alr[im], bf[in], acc[im][in], 0, 0, 0);
        if (NTERMS == 3)
          acc[im][in] = __builtin_amdgcn_mfma_f32_16x16x32_f16(af[im], blr[in], acc[im][in], 0, 0, 0);
      }
    __syncthreads();
  }
  float phiK = 0.0f;
  if (EPI == 1) phiK = phi_p[0] * 65536.0f;   // dot/65536 >= phi  <=>  dot >= phi*65536 (exact, pow2)
#pragma unroll
  for (int im = 0; im < 4; ++im) {
#pragma unroll
    for (int in = 0; in < 4; ++in) {
      int nn = n0 + wn * 64 + in * 16 + mr;
      int mb = m0 + wm * 64 + im * 16 + quad * 4;
      if (EPI == 1) {
        u64 bal[4];
#pragma unroll
        for (int r = 0; r < 4; ++r) {
          int m = mb + r;
          bool one = (acc[im][in][r] >= phiK) || (m == nn);   // diag forced to 1
          bal[r] = __ballot(one);
        }
#pragma unroll
        for (int r = 0; r < 4; ++r) {
          if (mr == 0) {
            u16 chunk = (u16)((bal[r] >> (16 * quad)) & 0xFFFFu);
            bitsOut[(size_t)(mb + r) * (Nn >> 4) + (nn >> 4)] = chunk;
          }
        }
        if (SYMM && m0 != n0) {
          // transposed chunk: row nn (by mr), 16 m-bits j=quad'*4+r'
          u32 tb = 0;
#pragma unroll
          for (int jb = 0; jb < 16; ++jb)
            tb |= (u32)((bal[jb & 3] >> ((jb >> 2) * 16 + mr)) & 1ull) << jb;
          if (quad == 0) {
            int nnr = n0 + wn * 64 + in * 16 + mr;
            int mch = (m0 + wm * 64 + im * 16) >> 4;
            bitsOut[(size_t)nnr * (Nn >> 4) + mch] = (u16)tb;
          }
        }
      } else {
#pragma unroll
        for (int r = 0; r < 4; ++r) {
          int m = mb + r;
          float v = acc[im][in][r];
          if (EPI == 0) {
            C[(size_t)m * Nn + nn] = v;
          } else if (EPI == 2) {
            C[(size_t)m * Nn + nn] = v * scale_m[m];
          } else {
            atomicAdd(&C[(size_t)m * Nn + nn], v * scale_m[m]);
          }
        }
      }
    }
  }
}

// ------------------------------------------------------------------
__global__ void k_split16(const float* __restrict__ src, f16* __restrict__ hi,
                          f16* __restrict__ lo) {
  int i = blockIdx.x * 256 + threadIdx.x;   // N*H
  float v = src[i];
  f16 h = (f16)v;
  hi[i] = h; lo[i] = (f16)(v - (float)h);
}

__global__ void k_degdis(const u32* __restrict__ bits, float* __restrict__ dis) {
  __shared__ int red[4];
  int row = blockIdx.x, tid = threadIdx.x;
  u32 w = bits[(size_t)row * 256 + tid];
  int c = __popc(w);
  for (int off = 32; off > 0; off >>= 1) c += __shfl_down(c, off);
  if ((tid & 63) == 0) red[tid >> 6] = c;
  __syncthreads();
  if (tid == 0) {
    int s = red[0] + red[1] + red[2] + red[3];
    dis[row] = s > 0 ? rsqrtf((float)s) : 0.0f;
  }
}

__global__ void k_outinit(const float* __restrict__ b, float* __restrict__ out) {
  int i = blockIdx.x * 256 + threadIdx.x;
  out[i] = b[i & (H_DIM - 1)];
}

// ------------------------------------------------------------------
extern "C" void kernel_launch(void* const* d_in, const int* in_sizes, int n_in,
                              void* d_out, int out_size, void* d_ws, size_t ws_size,
                              hipStream_t stream) {
  (void)in_sizes; (void)n_in; (void)out_size; (void)ws_size;
  const float* x    = (const float*)d_in[0];
  const int*   he   = (const int*)d_in[1];
  const int*   slen = (const int*)d_in[2];
  const float* h0   = (const float*)d_in[3];
  const float* wih  = (const float*)d_in[4];
  const float* whh  = (const float*)d_in[5];
  const float* bih  = (const float*)d_in[6];
  const float* bhh  = (const float*)d_in[7];
  const float* hw[3] = {(const float*)d_in[8], (const float*)d_in[10], (const float*)d_in[12]};
  const float* hb[3] = {(const float*)d_in[9], (const float*)d_in[11], (const float*)d_in[13]};
  const float* phi  = (const float*)d_in[14];
  const float* gw   = (const float*)d_in[15];
  const float* gb   = (const float*)d_in[16];
  float* out = (float*)d_out;

  // ---- workspace layout, everything re-initialized every call ----
  size_t off = 0;
  char* wsb = (char*)d_ws;
  auto alloc = [&](size_t b) { void* p = wsb + off; off += (b + 255) & ~(size_t)255; return p; };
  int*   order = (int*)alloc(N_NODES * 4);
  int*   lens  = (int*)alloc(N_NODES * 4);
  int*   Mts   = (int*)alloc(256);
  u32*   histD = (u32*)alloc(N_NODES * 4);
  u32*   histB = (u32*)alloc(N_EDGES * 4);
  float* dinv  = (float*)alloc(N_NODES * 4);
  float* binv  = (float*)alloc(N_EDGES * 4);
  float* dis   = (float*)alloc(N_NODES * 4);
  int*   noff  = (int*)alloc((N_NODES + 1) * 4);
  int*   eoff  = (int*)alloc((N_EDGES + 1) * 4);
  int*   ncur  = (int*)alloc(N_NODES * 4);
  int*   ecur  = (int*)alloc(N_EDGES * 4);
  int*   nlist = (int*)alloc(NNZ_ * 4);
  int*   elist = (int*)alloc(NNZ_ * 4);
  f16*   wihp  = (f16*)alloc(768 * 256 * 2);   // packed fragment-order weights
  f16*   whhp  = (f16*)alloc(768 * 256 * 2);
  f16*   hwT[3]; f16* hwTlo[3];
  for (int c = 0; c < 3; ++c) {
    hwT[c]   = (f16*)alloc(256 * 256 * 2);
    hwTlo[c] = (f16*)alloc(256 * 256 * 2);
  }
  f16*   gwT   = (f16*)alloc(256 * 256 * 2);
  f16*   gwTlo = (f16*)alloc(256 * 256 * 2);
  float* oA    = (float*)alloc((size_t)N_NODES * H_DIM * 4);   // `last`, then o2
  float* oB    = (float*)alloc((size_t)N_NODES * H_DIM * 4);   // o1, then o3
  float* xwb   = (float*)alloc((size_t)N_NODES * H_DIM * 4);   // xw scratch / z
  float* eb    = (float*)alloc((size_t)N_EDGES * H_DIM * 4);
  f16*   o3hi  = (f16*)alloc((size_t)N_NODES * H_DIM * 2);
  f16*   o3lo  = (f16*)alloc((size_t)N_NODES * H_DIM * 2);
  f16*   z16T  = (f16*)alloc((size_t)H_DIM * N_NODES * 2);     // z^T [256][8192]
  u32*   Abits = (u32*)alloc((size_t)N_NODES * 256 * 4);       // 8192x8192 bits

  // ---- preprocessing ----
  k_sort<<<1, 256, 0, stream>>>(slen, order, lens, Mts);
  k_wpack<<<768, 256, 0, stream>>>(wih, whh, wihp, whhp);
  hipMemsetAsync(histD, 0, N_NODES * 4, stream);
  hipMemsetAsync(histB, 0, N_EDGES * 4, stream);
  k_hist<<<NNZ_ / 256, 256, 0, stream>>>(he, histD, histB);
  k_inv<<<N_NODES / 256, 256, 0, stream>>>(histD, histB, dinv, binv);
  k_scan<<<1, 256, 0, stream>>>(histD, histB, noff, eoff, ncur, ecur);
  k_fill<<<NNZ_ / 256, 256, 0, stream>>>(he, ncur, ecur, nlist, elist);
  for (int c = 0; c < 3; ++c)
    k_tsplit<<<dim3(4, 4), 256, 0, stream>>>(hw[c], hwT[c], hwTlo[c], 256, 256, 1);
  k_tsplit<<<dim3(4, 4), 256, 0, stream>>>(gw, gwT, gwTlo, 256, 256, 1);

  // ---- GRU: ONE persistent launch, all 32 steps, h resident in LDS ----
  k_gru_all<<<N_NODES / 32, 512, 0, stream>>>(x, h0, oA, wihp, whhp,
                                              bih, bhh, order, lens);
  // oA now holds `last` in original node order.

  // ---- 3x HypergraphConv with residual (CSR gather, no atomics) ----
  float* prev = oA; float* nxt = oB;
  for (int c = 0; c < 3; ++c) {
    k_gemm<0, 3, 0, 0><<<dim3(2, 64, 1), 256, 0, stream>>>(
        prev, nullptr, nullptr, nullptr, hwT[c], hwTlo[c], xwb, nullptr,
        nullptr, nullptr, N_NODES, H_DIM, H_DIM, H_DIM);
    k_edge_gather<<<N_EDGES, 256, 0, stream>>>(xwb, eoff, nlist, binv, eb);
    k_node_gather<<<N_NODES, 256, 0, stream>>>(eb, noff, elist, dinv, prev, hb[c], nxt);
    float* tmp = prev; prev = nxt; nxt = tmp;
  }
  float* o3 = prev;  // == oB after 3 swaps

  // ---- dynamic adjacency: gram -> bitmask (triangular + mirrored), degrees ----
  k_split16<<<N_NODES, 256, 0, stream>>>(o3, o3hi, o3lo);
  k_gemm<2, 3, 1, 1><<<dim3(64, 64, 1), 256, 0, stream>>>(
      nullptr, o3hi, o3lo, nullptr, o3hi, o3lo, nullptr, (u16*)Abits,
      nullptr, phi, N_NODES, N_NODES, H_DIM, H_DIM);
  k_degdis<<<N_NODES, 256, 0, stream>>>(Abits, dis);

  // ---- z = dis .* (o3 @ gcn_w), then transpose-split to z16T ----
  k_gemm<2, 3, 2, 0><<<dim3(2, 64, 1), 256, 0, stream>>>(
      nullptr, o3hi, o3lo, nullptr, gwT, gwTlo, xwb, nullptr,
      dis, nullptr, N_NODES, H_DIM, H_DIM, H_DIM);
  k_tsplit<<<dim3(128, 4), 256, 0, stream>>>(xwb, z16T, nullptr, N_NODES, H_DIM, 0);

  // ---- out = dis .* (A @ z) + gcn_b  (bitmask A in LDS, split-K=4) ----
  k_outinit<<<N_NODES, 256, 0, stream>>>(gb, out);
  k_gemm<1, 1, 3, 0><<<dim3(2, 64, 4), 256, 0, stream>>>(
      nullptr, nullptr, nullptr, Abits, z16T, nullptr, out, nullptr,
      dis, nullptr, N_NODES, H_DIM, N_NODES, N_NODES / 4);
}